// Round 2
// baseline (11268.463 us; speedup 1.0000x reference)
//
#include <hip/hip_runtime.h>
#include <math.h>

#define H_ 128
#define NN 50000
#define NE 800000
#define TILE 64

typedef unsigned short u16;

__device__ __forceinline__ float red32(float v) {
  v += __shfl_xor(v, 1);
  v += __shfl_xor(v, 2);
  v += __shfl_xor(v, 4);
  v += __shfl_xor(v, 8);
  v += __shfl_xor(v, 16);
  return v;
}
__device__ __forceinline__ float red64(float v) { v = red32(v); v += __shfl_xor(v, 32); return v; }
__device__ __forceinline__ float sigm(float x) { return 1.0f / (1.0f + __expf(-x)); }
__device__ __forceinline__ float bf2f(u16 s) { return __uint_as_float(((unsigned)s) << 16); }
__device__ __forceinline__ u16 f2bf(float f) {
  unsigned u = __float_as_uint(f);
  return (u16)((u + 0x7FFFu + ((u >> 16) & 1u)) >> 16);
}

#define FMA16(acc, x0, x1, x2, x3, wv) \
  acc[0][0] = fmaf(x0, wv.x, acc[0][0]); acc[0][1] = fmaf(x0, wv.y, acc[0][1]); \
  acc[0][2] = fmaf(x0, wv.z, acc[0][2]); acc[0][3] = fmaf(x0, wv.w, acc[0][3]); \
  acc[1][0] = fmaf(x1, wv.x, acc[1][0]); acc[1][1] = fmaf(x1, wv.y, acc[1][1]); \
  acc[1][2] = fmaf(x1, wv.z, acc[1][2]); acc[1][3] = fmaf(x1, wv.w, acc[1][3]); \
  acc[2][0] = fmaf(x2, wv.x, acc[2][0]); acc[2][1] = fmaf(x2, wv.y, acc[2][1]); \
  acc[2][2] = fmaf(x2, wv.z, acc[2][2]); acc[2][3] = fmaf(x2, wv.w, acc[2][3]); \
  acc[3][0] = fmaf(x3, wv.x, acc[3][0]); acc[3][1] = fmaf(x3, wv.y, acc[3][1]); \
  acc[3][2] = fmaf(x3, wv.z, acc[3][2]); acc[3][3] = fmaf(x3, wv.w, acc[3][3]);

__global__ void k_sentinel(float* __restrict__ out, int n) {
  int i = blockIdx.x * 256 + threadIdx.x;
  if (i < n) out[i] = 3.0e30f;
}

// h = LN(relu(x @ W11 + b11); ln1) @ W12 + b12      [one wave per node]
__global__ __launch_bounds__(256) void k_node_enc(
    const float* __restrict__ x,
    const float* __restrict__ W11, const float* __restrict__ b11,
    const float* __restrict__ W12, const float* __restrict__ b12,
    const float* __restrict__ g1, const float* __restrict__ be1,
    float* __restrict__ h)
{
  __shared__ float sx[4][64];
  __shared__ float sv[4][130];
  const int w = threadIdx.x >> 6, lane = threadIdx.x & 63;
  const int node = blockIdx.x * 4 + w;
  sx[w][lane] = x[(size_t)node * 64 + lane];
  __syncthreads();
  const int t0 = lane * 2;
  float a0 = b11[t0], a1 = b11[t0 + 1];
#pragma unroll 8
  for (int k = 0; k < 64; ++k) {
    const float xk = sx[w][k];
    const float2 ww = *(const float2*)(W11 + (size_t)k * H_ + t0);
    a0 = fmaf(xk, ww.x, a0);
    a1 = fmaf(xk, ww.y, a1);
  }
  a0 = fmaxf(a0, 0.f); a1 = fmaxf(a1, 0.f);
  const float s = red64(a0 + a1);
  const float q = red64(a0 * a0 + a1 * a1);
  const float mean = s * (1.f / H_);
  const float rs = rsqrtf(q * (1.f / H_) - mean * mean + 1e-5f);
  sv[w][t0]     = (a0 - mean) * rs * g1[t0]     + be1[t0];
  sv[w][t0 + 1] = (a1 - mean) * rs * g1[t0 + 1] + be1[t0 + 1];
  __syncthreads();
  float c0 = b12[t0], c1 = b12[t0 + 1];
#pragma unroll 8
  for (int k = 0; k < H_; ++k) {
    const float vk = sv[w][k];
    const float2 ww = *(const float2*)(W12 + (size_t)k * H_ + t0);
    c0 = fmaf(vk, ww.x, c0);
    c1 = fmaf(vk, ww.y, c1);
  }
  h[(size_t)node * H_ + t0] = c0;
  h[(size_t)node * H_ + t0 + 1] = c1;
}

// e = LN(relu(ea @ W21 + b21); ln2) @ W22 + b22   [64-edge tile, W via L1]
__global__ __launch_bounds__(512) void k_edge_enc(
    const float* __restrict__ ea,
    const float* __restrict__ W21, const float* __restrict__ b21,
    const float* __restrict__ W22, const float* __restrict__ b22,
    const float* __restrict__ g2, const float* __restrict__ be2,
    u16* __restrict__ e)
{
  __shared__ float sEA[TILE][36];
  __shared__ float sLN[TILE][130];
  const int tid = threadIdx.x;
  const int eg = tid >> 5, og = tid & 31;
  const int eg4 = eg * 4, t0 = og * 4;
  const size_t base = (size_t)blockIdx.x * TILE;
  {
    const int edge = tid >> 3, c4 = tid & 7;
    const float4 v = *(const float4*)(ea + (base + edge) * 32 + c4 * 4);
    *(float4*)(&sEA[edge][c4 * 4]) = v;
  }
  __syncthreads();

  const float4 b1 = *(const float4*)(b21 + t0);
  float a[4][4];
#pragma unroll
  for (int i = 0; i < 4; ++i) { a[i][0] = b1.x; a[i][1] = b1.y; a[i][2] = b1.z; a[i][3] = b1.w; }
#pragma unroll 8
  for (int k = 0; k < 32; ++k) {
    const float4 wv = *(const float4*)(W21 + (size_t)k * H_ + t0);
    const float x0 = sEA[eg4][k], x1 = sEA[eg4 + 1][k], x2 = sEA[eg4 + 2][k], x3 = sEA[eg4 + 3][k];
    FMA16(a, x0, x1, x2, x3, wv)
  }
  const float4 g4 = *(const float4*)(g2 + t0);
  const float4 bb = *(const float4*)(be2 + t0);
#pragma unroll
  for (int i = 0; i < 4; ++i) {
    const float r0 = fmaxf(a[i][0], 0.f), r1 = fmaxf(a[i][1], 0.f);
    const float r2 = fmaxf(a[i][2], 0.f), r3 = fmaxf(a[i][3], 0.f);
    const float s = red32(r0 + r1 + r2 + r3);
    const float q = red32(r0 * r0 + r1 * r1 + r2 * r2 + r3 * r3);
    const float mean = s * (1.f / H_);
    const float rs = rsqrtf(q * (1.f / H_) - mean * mean + 1e-5f);
    sLN[eg4 + i][t0]     = (r0 - mean) * rs * g4.x + bb.x;
    sLN[eg4 + i][t0 + 1] = (r1 - mean) * rs * g4.y + bb.y;
    sLN[eg4 + i][t0 + 2] = (r2 - mean) * rs * g4.z + bb.z;
    sLN[eg4 + i][t0 + 3] = (r3 - mean) * rs * g4.w + bb.w;
  }
  __syncthreads();

  const float4 b2 = *(const float4*)(b22 + t0);
  float c[4][4];
#pragma unroll
  for (int i = 0; i < 4; ++i) { c[i][0] = b2.x; c[i][1] = b2.y; c[i][2] = b2.z; c[i][3] = b2.w; }
#pragma unroll 4
  for (int k = 0; k < H_; ++k) {
    const float4 wv = *(const float4*)(W22 + (size_t)k * H_ + t0);
    const float x0 = sLN[eg4][k], x1 = sLN[eg4 + 1][k], x2 = sLN[eg4 + 2][k], x3 = sLN[eg4 + 3][k];
    FMA16(c, x0, x1, x2, x3, wv)
  }
#pragma unroll
  for (int i = 0; i < 4; ++i) {
    ushort4 pk;
    pk.x = f2bf(c[i][0]); pk.y = f2bf(c[i][1]); pk.z = f2bf(c[i][2]); pk.w = f2bf(c[i][3]);
    *(ushort4*)(e + (base + eg4 + i) * H_ + t0) = pk;
  }
}

// {A1h(f32), A2h, A3h, B2h, B3h (bf16)} = h @ {Aw0,Aw1,Aw2,Bw1,Bw2} + bias
__global__ __launch_bounds__(512) void k_node_mats(
    const float* __restrict__ h,
    const float* __restrict__ Aw, const float* __restrict__ Ab,
    const float* __restrict__ Bw, const float* __restrict__ Bb,
    int l,
    float* __restrict__ A1h, u16* __restrict__ A2h, u16* __restrict__ A3h,
    u16* __restrict__ B2h, u16* __restrict__ B3h)
{
  __shared__ float sA[TILE][132];
  const int tid = threadIdx.x;
  const int eg = tid >> 5, og = tid & 31;
  const int eg4 = eg * 4, t0 = og * 4;
  const size_t base = (size_t)blockIdx.x * TILE;
#pragma unroll
  for (int p = 0; p < 4; ++p) {
    const int fid = tid + p * 512;
    const int r = fid >> 5, c4 = fid & 31;
    const float4 v = *(const float4*)(h + (base + r) * H_ + c4 * 4);  // tail rows read scratch, unused
    *(float4*)(&sA[r][c4 * 4]) = v;
  }
  __syncthreads();

  const float* Wm[5]; const float* bm[5];
  Wm[0] = Aw + ((size_t)l * 3 + 0) * H_ * H_; bm[0] = Ab + ((size_t)l * 3 + 0) * H_;
  Wm[1] = Aw + ((size_t)l * 3 + 1) * H_ * H_; bm[1] = Ab + ((size_t)l * 3 + 1) * H_;
  Wm[2] = Aw + ((size_t)l * 3 + 2) * H_ * H_; bm[2] = Ab + ((size_t)l * 3 + 2) * H_;
  Wm[3] = Bw + ((size_t)l * 3 + 1) * H_ * H_; bm[3] = Bb + ((size_t)l * 3 + 1) * H_;
  Wm[4] = Bw + ((size_t)l * 3 + 2) * H_ * H_; bm[4] = Bb + ((size_t)l * 3 + 2) * H_;
  u16* om[5] = {0, A2h, A3h, B2h, B3h};

#pragma unroll 1
  for (int m = 0; m < 5; ++m) {
    const float4 bi = *(const float4*)(bm[m] + t0);
    float acc[4][4];
#pragma unroll
    for (int i = 0; i < 4; ++i) { acc[i][0] = bi.x; acc[i][1] = bi.y; acc[i][2] = bi.z; acc[i][3] = bi.w; }
    const float* W = Wm[m];
#pragma unroll 4
    for (int k = 0; k < H_; ++k) {
      const float4 wv = *(const float4*)(W + (size_t)k * H_ + t0);
      const float x0 = sA[eg4][k], x1 = sA[eg4 + 1][k], x2 = sA[eg4 + 2][k], x3 = sA[eg4 + 3][k];
      FMA16(acc, x0, x1, x2, x3, wv)
    }
#pragma unroll
    for (int i = 0; i < 4; ++i) {
      const size_t n = base + eg4 + i;
      if (n < (size_t)NN) {
        if (m == 0) {
          *(float4*)(A1h + n * H_ + t0) = make_float4(acc[i][0], acc[i][1], acc[i][2], acc[i][3]);
        } else {
          ushort4 pk;
          pk.x = f2bf(acc[i][0]); pk.y = f2bf(acc[i][1]); pk.z = f2bf(acc[i][2]); pk.w = f2bf(acc[i][3]);
          *(ushort4*)(om[m] + n * H_ + t0) = pk;
        }
      }
    }
  }
}

// gated edge layer: b1e GEMM + gathers + 2x(relu,LN,residual,sigmoid) + atomics into A1h
__global__ __launch_bounds__(512) void k_layer_edge(
    u16* __restrict__ e,
    const int* __restrict__ rowp, const int* __restrict__ colp,
    const float* __restrict__ Bw0, const float* __restrict__ Bb0,
    const u16* __restrict__ A2h, const u16* __restrict__ A3h,
    const u16* __restrict__ B2h, const u16* __restrict__ B3h,
    const float* __restrict__ lng, const float* __restrict__ lnb,
    float* __restrict__ A1h)
{
  __shared__ float sE[TILE][132];
  const int tid = threadIdx.x;
  const int eg = tid >> 5, og = tid & 31;
  const int eg4 = eg * 4, t0 = og * 4;
  const size_t base = (size_t)blockIdx.x * TILE;
#pragma unroll
  for (int p = 0; p < 4; ++p) {
    const int fid = tid + p * 512;
    const int edge = fid >> 5, c4 = fid & 31;
    const ushort4 u = *(const ushort4*)(e + (base + edge) * H_ + c4 * 4);
    sE[edge][c4 * 4]     = bf2f(u.x);
    sE[edge][c4 * 4 + 1] = bf2f(u.y);
    sE[edge][c4 * 4 + 2] = bf2f(u.z);
    sE[edge][c4 * 4 + 3] = bf2f(u.w);
  }
  __syncthreads();

  const float4 bb = *(const float4*)(Bb0 + t0);
  float b1e[4][4];
#pragma unroll
  for (int i = 0; i < 4; ++i) { b1e[i][0] = bb.x; b1e[i][1] = bb.y; b1e[i][2] = bb.z; b1e[i][3] = bb.w; }
#pragma unroll 4
  for (int k = 0; k < H_; ++k) {
    const float4 wv = *(const float4*)(Bw0 + (size_t)k * H_ + t0);
    const float x0 = sE[eg4][k], x1 = sE[eg4 + 1][k], x2 = sE[eg4 + 2][k], x3 = sE[eg4 + 3][k];
    FMA16(b1e, x0, x1, x2, x3, wv)
  }

  const float4 g4  = *(const float4*)(lng + t0);
  const float4 lb4 = *(const float4*)(lnb + t0);
#pragma unroll 1
  for (int i = 0; i < 4; ++i) {
    const size_t eid = base + eg4 + i;
    const int r = rowp[eid], c = colp[eid];
    const ushort4 ub2r = *(const ushort4*)(B2h + (size_t)r * H_ + t0);
    const ushort4 ub3c = *(const ushort4*)(B3h + (size_t)c * H_ + t0);
    const ushort4 ub2c = *(const ushort4*)(B2h + (size_t)c * H_ + t0);
    const ushort4 ub3r = *(const ushort4*)(B3h + (size_t)r * H_ + t0);
    const ushort4 ua2r = *(const ushort4*)(A2h + (size_t)r * H_ + t0);
    const ushort4 ua3c = *(const ushort4*)(A3h + (size_t)c * H_ + t0);
    float pji[4], pik[4];
    pji[0] = fmaxf(b1e[i][0] + bf2f(ub2r.x) + bf2f(ub3c.x), 0.f);
    pji[1] = fmaxf(b1e[i][1] + bf2f(ub2r.y) + bf2f(ub3c.y), 0.f);
    pji[2] = fmaxf(b1e[i][2] + bf2f(ub2r.z) + bf2f(ub3c.z), 0.f);
    pji[3] = fmaxf(b1e[i][3] + bf2f(ub2r.w) + bf2f(ub3c.w), 0.f);
    pik[0] = fmaxf(b1e[i][0] + bf2f(ub2c.x) + bf2f(ub3r.x), 0.f);
    pik[1] = fmaxf(b1e[i][1] + bf2f(ub2c.y) + bf2f(ub3r.y), 0.f);
    pik[2] = fmaxf(b1e[i][2] + bf2f(ub2c.z) + bf2f(ub3r.z), 0.f);
    pik[3] = fmaxf(b1e[i][3] + bf2f(ub2c.w) + bf2f(ub3r.w), 0.f);
    const float sji = red32(pji[0] + pji[1] + pji[2] + pji[3]);
    const float qji = red32(pji[0]*pji[0] + pji[1]*pji[1] + pji[2]*pji[2] + pji[3]*pji[3]);
    const float sik = red32(pik[0] + pik[1] + pik[2] + pik[3]);
    const float qik = red32(pik[0]*pik[0] + pik[1]*pik[1] + pik[2]*pik[2] + pik[3]*pik[3]);
    const float mji = sji * (1.f / H_);
    const float rji = rsqrtf(qji * (1.f / H_) - mji * mji + 1e-5f);
    const float mik = sik * (1.f / H_);
    const float rik = rsqrtf(qik * (1.f / H_) - mik * mik + 1e-5f);
    const float eo0 = sE[eg4 + i][t0], eo1 = sE[eg4 + i][t0 + 1];
    const float eo2 = sE[eg4 + i][t0 + 2], eo3 = sE[eg4 + i][t0 + 3];
    float eji[4], eik[4];
    eji[0] = eo0 + (pji[0] - mji) * rji * g4.x + lb4.x;
    eji[1] = eo1 + (pji[1] - mji) * rji * g4.y + lb4.y;
    eji[2] = eo2 + (pji[2] - mji) * rji * g4.z + lb4.z;
    eji[3] = eo3 + (pji[3] - mji) * rji * g4.w + lb4.w;
    eik[0] = eo0 + (pik[0] - mik) * rik * g4.x + lb4.x;
    eik[1] = eo1 + (pik[1] - mik) * rik * g4.y + lb4.y;
    eik[2] = eo2 + (pik[2] - mik) * rik * g4.z + lb4.z;
    eik[3] = eo3 + (pik[3] - mik) * rik * g4.w + lb4.w;
    const float sgji0 = sigm(eji[0]), sgji1 = sigm(eji[1]), sgji2 = sigm(eji[2]), sgji3 = sigm(eji[3]);
    const float sgik0 = sigm(eik[0]), sgik1 = sigm(eik[1]), sgik2 = sigm(eik[2]), sgik3 = sigm(eik[3]);
    const float Sji = red32(sgji0 + sgji1 + sgji2 + sgji3);
    const float Sik = red32(sgik0 + sgik1 + sgik2 + sgik3);
    const float iji = 1.f / (Sji + 1e-6f);
    const float iik = 1.f / (Sik + 1e-6f);
    float* accc = A1h + (size_t)c * H_ + t0;
    float* accr = A1h + (size_t)r * H_ + t0;
    atomicAdd(accc + 0, bf2f(ua2r.x) * sgji0 * iji);
    atomicAdd(accc + 1, bf2f(ua2r.y) * sgji1 * iji);
    atomicAdd(accc + 2, bf2f(ua2r.z) * sgji2 * iji);
    atomicAdd(accc + 3, bf2f(ua2r.w) * sgji3 * iji);
    atomicAdd(accr + 0, bf2f(ua3c.x) * sgik0 * iik);
    atomicAdd(accr + 1, bf2f(ua3c.y) * sgik1 * iik);
    atomicAdd(accr + 2, bf2f(ua3c.z) * sgik2 * iik);
    atomicAdd(accr + 3, bf2f(ua3c.w) * sgik3 * iik);
    ushort4 pk;
    pk.x = f2bf(eji[0]); pk.y = f2bf(eji[1]); pk.z = f2bf(eji[2]); pk.w = f2bf(eji[3]);
    *(ushort4*)(e + eid * H_ + t0) = pk;
  }
}

// h += LN(relu(A1h_with_messages); lnh)   [one wave per node]
__global__ __launch_bounds__(256) void k_node_update(
    float* __restrict__ h, const float* __restrict__ A1h,
    const float* __restrict__ g, const float* __restrict__ b)
{
  const int w = threadIdx.x >> 6, lane = threadIdx.x & 63;
  const size_t node = (size_t)blockIdx.x * 4 + w;
  const int t0 = lane * 2;
  const float2 a = *(const float2*)(A1h + node * H_ + t0);
  const float u0 = fmaxf(a.x, 0.f);
  const float u1 = fmaxf(a.y, 0.f);
  const float sm = red64(u0 + u1);
  const float sq = red64(u0 * u0 + u1 * u1);
  const float mean = sm * (1.f / H_);
  const float rs = rsqrtf(sq * (1.f / H_) - mean * mean + 1e-5f);
  float2 hv = *(float2*)(h + node * H_ + t0);
  hv.x += (u0 - mean) * rs * g[t0] + b[t0];
  hv.y += (u1 - mean) * rs * g[t0 + 1] + b[t0 + 1];
  *(float2*)(h + node * H_ + t0) = hv;
}

// score = relu([h[row],h[col],e] @ s1 + b1) @ s2 + b2
__global__ __launch_bounds__(512) void k_score(
    const u16* __restrict__ e, const int* __restrict__ rowp, const int* __restrict__ colp,
    const float* __restrict__ h,
    const float* __restrict__ s1w, const float* __restrict__ s1b,
    const float* __restrict__ s2w, const float* __restrict__ s2b,
    float* __restrict__ out)
{
  __shared__ float sA[TILE][132];
  const int tid = threadIdx.x;
  const int eg = tid >> 5, og = tid & 31;
  const int eg4 = eg * 4, t0 = og * 4;
  const size_t base = (size_t)blockIdx.x * TILE;
  float accm[4][4] = {{0.f}};

#pragma unroll 1
  for (int qq = 0; qq < 3; ++qq) {
    __syncthreads();
#pragma unroll
    for (int p = 0; p < 4; ++p) {
      const int fid = tid + p * 512;
      const int edge = fid >> 5, c4 = fid & 31;
      if (qq == 2) {
        const ushort4 u = *(const ushort4*)(e + (base + edge) * H_ + c4 * 4);
        sA[edge][c4 * 4]     = bf2f(u.x);
        sA[edge][c4 * 4 + 1] = bf2f(u.y);
        sA[edge][c4 * 4 + 2] = bf2f(u.z);
        sA[edge][c4 * 4 + 3] = bf2f(u.w);
      } else {
        const int n = (qq == 0) ? rowp[base + edge] : colp[base + edge];
        const float4 v = *(const float4*)(h + (size_t)n * H_ + c4 * 4);
        *(float4*)(&sA[edge][c4 * 4]) = v;
      }
    }
    __syncthreads();
    const float* W = s1w + (size_t)qq * H_ * H_;
#pragma unroll 4
    for (int k = 0; k < H_; ++k) {
      const float4 wv = *(const float4*)(W + (size_t)k * H_ + t0);
      const float x0 = sA[eg4][k], x1 = sA[eg4 + 1][k], x2 = sA[eg4 + 2][k], x3 = sA[eg4 + 3][k];
      FMA16(accm, x0, x1, x2, x3, wv)
    }
  }

  const float4 sb = *(const float4*)(s1b + t0);
  const float4 w2 = *(const float4*)(s2w + t0);
  const float b2 = s2b[0];
#pragma unroll
  for (int i = 0; i < 4; ++i) {
    float p = fmaxf(accm[i][0] + sb.x, 0.f) * w2.x
            + fmaxf(accm[i][1] + sb.y, 0.f) * w2.y
            + fmaxf(accm[i][2] + sb.z, 0.f) * w2.z
            + fmaxf(accm[i][3] + sb.w, 0.f) * w2.w;
    p = red32(p);
    if (og == 0) out[base + eg4 + i] = p + b2;
  }
}

extern "C" void kernel_launch(void* const* d_in, const int* in_sizes, int n_in,
                              void* d_out, int out_size, void* d_ws, size_t ws_size,
                              hipStream_t stream) {
  const float* x    = (const float*)d_in[0];
  const float* ea   = (const float*)d_in[1];
  const int*   eidx = (const int*)d_in[2];
  const float* W11w = (const float*)d_in[3];
  const float* W11b = (const float*)d_in[4];
  const float* W12w = (const float*)d_in[5];
  const float* W12b = (const float*)d_in[6];
  const float* W21w = (const float*)d_in[7];
  const float* W21b = (const float*)d_in[8];
  const float* W22w = (const float*)d_in[9];
  const float* W22b = (const float*)d_in[10];
  const float* ln1g = (const float*)d_in[11];
  const float* ln1b = (const float*)d_in[12];
  const float* ln2g = (const float*)d_in[13];
  const float* ln2b = (const float*)d_in[14];
  const float* Aw   = (const float*)d_in[15];
  const float* Ab   = (const float*)d_in[16];
  const float* Bw   = (const float*)d_in[17];
  const float* Bb   = (const float*)d_in[18];
  const float* lnhg = (const float*)d_in[19];
  const float* lnhb = (const float*)d_in[20];
  const float* lneg = (const float*)d_in[21];
  const float* lneb = (const float*)d_in[22];
  const float* s1w  = (const float*)d_in[23];
  const float* s1b  = (const float*)d_in[24];
  const float* s2w  = (const float*)d_in[25];
  const float* s2b  = (const float*)d_in[26];
  float* out = (float*)d_out;

  // diagnostic sentinel: if the pipeline below runs, k_score overwrites all of it
  k_sentinel<<<(out_size + 255) / 256, 256, 0, stream>>>(out, out_size);

  // workspace layout (bf16 e + bf16 gather tables): 307.2 MB total
  const size_t need = 307200000;
  if (ws_size < need) return;  // sentinel (3e30) signals this case

  char* wsb = (char*)d_ws;
  u16*   e   = (u16*)wsb;                        // [NE][128] bf16   204.8 MB
  float* h   = (float*)(wsb + 204800000);        // [NN][128] f32     25.6 MB
  float* A1h = (float*)(wsb + 230400000);        // [NN][128] f32     25.6 MB (gemm + atomic msgs)
  u16*   A2h = (u16*)(wsb + 256000000);          // [NN][128] bf16    12.8 MB
  u16*   A3h = (u16*)(wsb + 268800000);
  u16*   B2h = (u16*)(wsb + 281600000);
  u16*   B3h = (u16*)(wsb + 294400000);

  const int* rowp = eidx;
  const int* colp = eidx + NE;

  k_node_enc<<<NN / 4, 256, 0, stream>>>(x, W11w, W11b, W12w, W12b, ln1g, ln1b, h);
  k_edge_enc<<<NE / TILE, 512, 0, stream>>>(ea, W21w, W21b, W22w, W22b, ln2g, ln2b, e);
  for (int l = 0; l < 3; ++l) {
    k_node_mats<<<(NN + TILE - 1) / TILE, 512, 0, stream>>>(h, Aw, Ab, Bw, Bb, l,
                                                            A1h, A2h, A3h, B2h, B3h);
    k_layer_edge<<<NE / TILE, 512, 0, stream>>>(e, rowp, colp,
        Bw + ((size_t)l * 3 + 0) * H_ * H_, Bb + ((size_t)l * 3 + 0) * H_,
        A2h, A3h, B2h, B3h, lneg + (size_t)l * H_, lneb + (size_t)l * H_, A1h);
    k_node_update<<<NN / 4, 256, 0, stream>>>(h, A1h,
        lnhg + (size_t)l * H_, lnhb + (size_t)l * H_);
  }
  k_score<<<NE / TILE, 512, 0, stream>>>(e, rowp, colp, h, s1w, s1b, s2w, s2b, out);
}

// Round 3
// 11265.616 us; speedup vs baseline: 1.0003x; 1.0003x over previous
//
#include <hip/hip_runtime.h>
#include <math.h>

#define H_ 128
#define NN 50000
#define NE 800000
#define TILE 64

typedef unsigned short u16;

__device__ __forceinline__ float red32(float v) {
  v += __shfl_xor(v, 1);
  v += __shfl_xor(v, 2);
  v += __shfl_xor(v, 4);
  v += __shfl_xor(v, 8);
  v += __shfl_xor(v, 16);
  return v;
}
__device__ __forceinline__ float red64(float v) { v = red32(v); v += __shfl_xor(v, 32); return v; }
__device__ __forceinline__ float sigm(float x) { return 1.0f / (1.0f + __expf(-x)); }
__device__ __forceinline__ float bf2f(u16 s) { return __uint_as_float(((unsigned)s) << 16); }
__device__ __forceinline__ u16 f2bf(float f) {
  unsigned u = __float_as_uint(f);
  return (u16)((u + 0x7FFFu + ((u >> 16) & 1u)) >> 16);
}

#define FMA16(acc, x0, x1, x2, x3, wv) \
  acc[0][0] = fmaf(x0, wv.x, acc[0][0]); acc[0][1] = fmaf(x0, wv.y, acc[0][1]); \
  acc[0][2] = fmaf(x0, wv.z, acc[0][2]); acc[0][3] = fmaf(x0, wv.w, acc[0][3]); \
  acc[1][0] = fmaf(x1, wv.x, acc[1][0]); acc[1][1] = fmaf(x1, wv.y, acc[1][1]); \
  acc[1][2] = fmaf(x1, wv.z, acc[1][2]); acc[1][3] = fmaf(x1, wv.w, acc[1][3]); \
  acc[2][0] = fmaf(x2, wv.x, acc[2][0]); acc[2][1] = fmaf(x2, wv.y, acc[2][1]); \
  acc[2][2] = fmaf(x2, wv.z, acc[2][2]); acc[2][3] = fmaf(x2, wv.w, acc[2][3]); \
  acc[3][0] = fmaf(x3, wv.x, acc[3][0]); acc[3][1] = fmaf(x3, wv.y, acc[3][1]); \
  acc[3][2] = fmaf(x3, wv.z, acc[3][2]); acc[3][3] = fmaf(x3, wv.w, acc[3][3]);

__global__ void k_sentinel(float* __restrict__ out, int n) {
  int i = blockIdx.x * 256 + threadIdx.x;
  if (i < n) out[i] = 3.0e30f;
}

// ---------------- sort machinery (once per call) ----------------

__global__ void k_count(const int* __restrict__ rowp, const int* __restrict__ colp,
                        int* __restrict__ cnt_row, int* __restrict__ cnt_col) {
  int i = blockIdx.x * 256 + threadIdx.x;
  if (i < NE) {
    atomicAdd(&cnt_col[colp[i]], 1);
    atomicAdd(&cnt_row[rowp[i]], 1);
  }
}

// exclusive scan of n ints; block 0: c0->o0, block 1: c1->o1. o has n+1 entries.
__global__ __launch_bounds__(1024) void k_scan2(
    const int* __restrict__ c0, int* __restrict__ o0,
    const int* __restrict__ c1, int* __restrict__ o1, int n)
{
  const int* c = blockIdx.x ? c1 : c0;
  int* o = blockIdx.x ? o1 : o0;
  __shared__ int warpsum[16];
  const int tid = threadIdx.x;
  int carry = 0;
  for (int basei = 0; basei < n; basei += 1024) {
    const int vidx = basei + tid;
    const int v = (vidx < n) ? c[vidx] : 0;
    int s = v;
#pragma unroll
    for (int d = 1; d < 64; d <<= 1) {
      int t = __shfl_up(s, d);
      if ((tid & 63) >= d) s += t;
    }
    if ((tid & 63) == 63) warpsum[tid >> 6] = s;
    __syncthreads();
    if (tid < 16) {
      int ws = warpsum[tid];
#pragma unroll
      for (int d = 1; d < 16; d <<= 1) {
        int t = __shfl_up(ws, d);
        if (tid >= d) ws += t;
      }
      warpsum[tid] = ws;  // inclusive over wave sums
    }
    __syncthreads();
    const int wave = tid >> 6;
    const int prefix = (wave == 0 ? 0 : warpsum[wave - 1]) + carry;
    if (vidx < n) o[vidx] = s - v + prefix;  // exclusive
    carry += warpsum[15];
    __syncthreads();
  }
  if (tid == 0) o[n] = carry;
}

__global__ void k_copy_cur(const int* __restrict__ oc, const int* __restrict__ orr,
                           int* __restrict__ cc, int* __restrict__ cr) {
  int i = blockIdx.x * 256 + threadIdx.x;
  if (i < NN) { cc[i] = oc[i]; cr[i] = orr[i]; }
}

__global__ void k_fill(const int* __restrict__ rowp, const int* __restrict__ colp,
                       int* __restrict__ cur_col, int* __restrict__ cur_row,
                       int* __restrict__ slot_ji, int* __restrict__ slot_ik) {
  int i = blockIdx.x * 256 + threadIdx.x;
  if (i < NE) {
    int p = atomicAdd(&cur_col[colp[i]], 1);
    slot_ji[p] = i;
    int q = atomicAdd(&cur_row[rowp[i]], 1);
    slot_ik[q] = i;
  }
}

// ---------------- encoders ----------------

__global__ __launch_bounds__(256) void k_node_enc(
    const float* __restrict__ x,
    const float* __restrict__ W11, const float* __restrict__ b11,
    const float* __restrict__ W12, const float* __restrict__ b12,
    const float* __restrict__ g1, const float* __restrict__ be1,
    float* __restrict__ h)
{
  __shared__ float sx[4][64];
  __shared__ float sv[4][130];
  const int w = threadIdx.x >> 6, lane = threadIdx.x & 63;
  const int node = blockIdx.x * 4 + w;
  sx[w][lane] = x[(size_t)node * 64 + lane];
  __syncthreads();
  const int t0 = lane * 2;
  float a0 = b11[t0], a1 = b11[t0 + 1];
#pragma unroll 8
  for (int k = 0; k < 64; ++k) {
    const float xk = sx[w][k];
    const float2 ww = *(const float2*)(W11 + (size_t)k * H_ + t0);
    a0 = fmaf(xk, ww.x, a0);
    a1 = fmaf(xk, ww.y, a1);
  }
  a0 = fmaxf(a0, 0.f); a1 = fmaxf(a1, 0.f);
  const float s = red64(a0 + a1);
  const float q = red64(a0 * a0 + a1 * a1);
  const float mean = s * (1.f / H_);
  const float rs = rsqrtf(q * (1.f / H_) - mean * mean + 1e-5f);
  sv[w][t0]     = (a0 - mean) * rs * g1[t0]     + be1[t0];
  sv[w][t0 + 1] = (a1 - mean) * rs * g1[t0 + 1] + be1[t0 + 1];
  __syncthreads();
  float c0 = b12[t0], c1 = b12[t0 + 1];
#pragma unroll 8
  for (int k = 0; k < H_; ++k) {
    const float vk = sv[w][k];
    const float2 ww = *(const float2*)(W12 + (size_t)k * H_ + t0);
    c0 = fmaf(vk, ww.x, c0);
    c1 = fmaf(vk, ww.y, c1);
  }
  h[(size_t)node * H_ + t0] = c0;
  h[(size_t)node * H_ + t0 + 1] = c1;
}

__global__ __launch_bounds__(512) void k_edge_enc(
    const float* __restrict__ ea,
    const float* __restrict__ W21, const float* __restrict__ b21,
    const float* __restrict__ W22, const float* __restrict__ b22,
    const float* __restrict__ g2, const float* __restrict__ be2,
    u16* __restrict__ e)
{
  __shared__ float sEA[TILE][36];
  __shared__ float sLN[TILE][130];
  const int tid = threadIdx.x;
  const int eg = tid >> 5, og = tid & 31;
  const int eg4 = eg * 4, t0 = og * 4;
  const size_t base = (size_t)blockIdx.x * TILE;
  {
    const int edge = tid >> 3, c4 = tid & 7;
    const float4 v = *(const float4*)(ea + (base + edge) * 32 + c4 * 4);
    *(float4*)(&sEA[edge][c4 * 4]) = v;
  }
  __syncthreads();

  const float4 b1 = *(const float4*)(b21 + t0);
  float a[4][4];
#pragma unroll
  for (int i = 0; i < 4; ++i) { a[i][0] = b1.x; a[i][1] = b1.y; a[i][2] = b1.z; a[i][3] = b1.w; }
#pragma unroll 8
  for (int k = 0; k < 32; ++k) {
    const float4 wv = *(const float4*)(W21 + (size_t)k * H_ + t0);
    const float x0 = sEA[eg4][k], x1 = sEA[eg4 + 1][k], x2 = sEA[eg4 + 2][k], x3 = sEA[eg4 + 3][k];
    FMA16(a, x0, x1, x2, x3, wv)
  }
  const float4 g4 = *(const float4*)(g2 + t0);
  const float4 bb = *(const float4*)(be2 + t0);
#pragma unroll
  for (int i = 0; i < 4; ++i) {
    const float r0 = fmaxf(a[i][0], 0.f), r1 = fmaxf(a[i][1], 0.f);
    const float r2 = fmaxf(a[i][2], 0.f), r3 = fmaxf(a[i][3], 0.f);
    const float s = red32(r0 + r1 + r2 + r3);
    const float q = red32(r0 * r0 + r1 * r1 + r2 * r2 + r3 * r3);
    const float mean = s * (1.f / H_);
    const float rs = rsqrtf(q * (1.f / H_) - mean * mean + 1e-5f);
    sLN[eg4 + i][t0]     = (r0 - mean) * rs * g4.x + bb.x;
    sLN[eg4 + i][t0 + 1] = (r1 - mean) * rs * g4.y + bb.y;
    sLN[eg4 + i][t0 + 2] = (r2 - mean) * rs * g4.z + bb.z;
    sLN[eg4 + i][t0 + 3] = (r3 - mean) * rs * g4.w + bb.w;
  }
  __syncthreads();

  const float4 b2 = *(const float4*)(b22 + t0);
  float c[4][4];
#pragma unroll
  for (int i = 0; i < 4; ++i) { c[i][0] = b2.x; c[i][1] = b2.y; c[i][2] = b2.z; c[i][3] = b2.w; }
#pragma unroll 4
  for (int k = 0; k < H_; ++k) {
    const float4 wv = *(const float4*)(W22 + (size_t)k * H_ + t0);
    const float x0 = sLN[eg4][k], x1 = sLN[eg4 + 1][k], x2 = sLN[eg4 + 2][k], x3 = sLN[eg4 + 3][k];
    FMA16(c, x0, x1, x2, x3, wv)
  }
#pragma unroll
  for (int i = 0; i < 4; ++i) {
    ushort4 pk;
    pk.x = f2bf(c[i][0]); pk.y = f2bf(c[i][1]); pk.z = f2bf(c[i][2]); pk.w = f2bf(c[i][3]);
    *(ushort4*)(e + (base + eg4 + i) * H_ + t0) = pk;
  }
}

// ---------------- per-layer node GEMMs ----------------

__global__ __launch_bounds__(512) void k_node_mats(
    const float* __restrict__ h,
    const float* __restrict__ Aw, const float* __restrict__ Ab,
    const float* __restrict__ Bw, const float* __restrict__ Bb,
    int l,
    float* __restrict__ A1h, u16* __restrict__ A2h, u16* __restrict__ A3h,
    u16* __restrict__ B2h, u16* __restrict__ B3h)
{
  __shared__ float sA[TILE][132];
  const int tid = threadIdx.x;
  const int eg = tid >> 5, og = tid & 31;
  const int eg4 = eg * 4, t0 = og * 4;
  const size_t base = (size_t)blockIdx.x * TILE;
#pragma unroll
  for (int p = 0; p < 4; ++p) {
    const int fid = tid + p * 512;
    const int r = fid >> 5, c4 = fid & 31;
    const float4 v = *(const float4*)(h + (base + r) * H_ + c4 * 4);
    *(float4*)(&sA[r][c4 * 4]) = v;
  }
  __syncthreads();

  const float* Wm[5]; const float* bm[5];
  Wm[0] = Aw + ((size_t)l * 3 + 0) * H_ * H_; bm[0] = Ab + ((size_t)l * 3 + 0) * H_;
  Wm[1] = Aw + ((size_t)l * 3 + 1) * H_ * H_; bm[1] = Ab + ((size_t)l * 3 + 1) * H_;
  Wm[2] = Aw + ((size_t)l * 3 + 2) * H_ * H_; bm[2] = Ab + ((size_t)l * 3 + 2) * H_;
  Wm[3] = Bw + ((size_t)l * 3 + 1) * H_ * H_; bm[3] = Bb + ((size_t)l * 3 + 1) * H_;
  Wm[4] = Bw + ((size_t)l * 3 + 2) * H_ * H_; bm[4] = Bb + ((size_t)l * 3 + 2) * H_;
  u16* om[5] = {0, A2h, A3h, B2h, B3h};

#pragma unroll 1
  for (int m = 0; m < 5; ++m) {
    const float4 bi = *(const float4*)(bm[m] + t0);
    float acc[4][4];
#pragma unroll
    for (int i = 0; i < 4; ++i) { acc[i][0] = bi.x; acc[i][1] = bi.y; acc[i][2] = bi.z; acc[i][3] = bi.w; }
    const float* W = Wm[m];
#pragma unroll 4
    for (int k = 0; k < H_; ++k) {
      const float4 wv = *(const float4*)(W + (size_t)k * H_ + t0);
      const float x0 = sA[eg4][k], x1 = sA[eg4 + 1][k], x2 = sA[eg4 + 2][k], x3 = sA[eg4 + 3][k];
      FMA16(acc, x0, x1, x2, x3, wv)
    }
#pragma unroll
    for (int i = 0; i < 4; ++i) {
      const size_t n = base + eg4 + i;
      if (n < (size_t)NN) {
        if (m == 0) {
          *(float4*)(A1h + n * H_ + t0) = make_float4(acc[i][0], acc[i][1], acc[i][2], acc[i][3]);
        } else {
          ushort4 pk;
          pk.x = f2bf(acc[i][0]); pk.y = f2bf(acc[i][1]); pk.z = f2bf(acc[i][2]); pk.w = f2bf(acc[i][3]);
          *(ushort4*)(om[m] + n * H_ + t0) = pk;
        }
      }
    }
  }
}

// ---------------- gated edge layer, sorted path (no atomics) ----------------

__global__ __launch_bounds__(512) void k_layer_edge_s(
    u16* __restrict__ e, u16* __restrict__ eik_buf,
    const int* __restrict__ rowp, const int* __restrict__ colp,
    const float* __restrict__ Bw0, const float* __restrict__ Bb0,
    const u16* __restrict__ B2h, const u16* __restrict__ B3h,
    const float* __restrict__ lng, const float* __restrict__ lnb)
{
  __shared__ float sE[TILE][132];
  const int tid = threadIdx.x;
  const int eg = tid >> 5, og = tid & 31;
  const int eg4 = eg * 4, t0 = og * 4;
  const size_t base = (size_t)blockIdx.x * TILE;
#pragma unroll
  for (int p = 0; p < 4; ++p) {
    const int fid = tid + p * 512;
    const int edge = fid >> 5, c4 = fid & 31;
    const ushort4 u = *(const ushort4*)(e + (base + edge) * H_ + c4 * 4);
    sE[edge][c4 * 4]     = bf2f(u.x);
    sE[edge][c4 * 4 + 1] = bf2f(u.y);
    sE[edge][c4 * 4 + 2] = bf2f(u.z);
    sE[edge][c4 * 4 + 3] = bf2f(u.w);
  }
  __syncthreads();

  const float4 bb = *(const float4*)(Bb0 + t0);
  float b1e[4][4];
#pragma unroll
  for (int i = 0; i < 4; ++i) { b1e[i][0] = bb.x; b1e[i][1] = bb.y; b1e[i][2] = bb.z; b1e[i][3] = bb.w; }
#pragma unroll 4
  for (int k = 0; k < H_; ++k) {
    const float4 wv = *(const float4*)(Bw0 + (size_t)k * H_ + t0);
    const float x0 = sE[eg4][k], x1 = sE[eg4 + 1][k], x2 = sE[eg4 + 2][k], x3 = sE[eg4 + 3][k];
    FMA16(b1e, x0, x1, x2, x3, wv)
  }

  const float4 g4  = *(const float4*)(lng + t0);
  const float4 lb4 = *(const float4*)(lnb + t0);
#pragma unroll 1
  for (int i = 0; i < 4; ++i) {
    const size_t eid = base + eg4 + i;
    const int r = rowp[eid], c = colp[eid];
    const ushort4 ub2r = *(const ushort4*)(B2h + (size_t)r * H_ + t0);
    const ushort4 ub3c = *(const ushort4*)(B3h + (size_t)c * H_ + t0);
    const ushort4 ub2c = *(const ushort4*)(B2h + (size_t)c * H_ + t0);
    const ushort4 ub3r = *(const ushort4*)(B3h + (size_t)r * H_ + t0);
    float pji[4], pik[4];
    pji[0] = fmaxf(b1e[i][0] + bf2f(ub2r.x) + bf2f(ub3c.x), 0.f);
    pji[1] = fmaxf(b1e[i][1] + bf2f(ub2r.y) + bf2f(ub3c.y), 0.f);
    pji[2] = fmaxf(b1e[i][2] + bf2f(ub2r.z) + bf2f(ub3c.z), 0.f);
    pji[3] = fmaxf(b1e[i][3] + bf2f(ub2r.w) + bf2f(ub3c.w), 0.f);
    pik[0] = fmaxf(b1e[i][0] + bf2f(ub2c.x) + bf2f(ub3r.x), 0.f);
    pik[1] = fmaxf(b1e[i][1] + bf2f(ub2c.y) + bf2f(ub3r.y), 0.f);
    pik[2] = fmaxf(b1e[i][2] + bf2f(ub2c.z) + bf2f(ub3r.z), 0.f);
    pik[3] = fmaxf(b1e[i][3] + bf2f(ub2c.w) + bf2f(ub3r.w), 0.f);
    const float sji = red32(pji[0] + pji[1] + pji[2] + pji[3]);
    const float qji = red32(pji[0]*pji[0] + pji[1]*pji[1] + pji[2]*pji[2] + pji[3]*pji[3]);
    const float sik = red32(pik[0] + pik[1] + pik[2] + pik[3]);
    const float qik = red32(pik[0]*pik[0] + pik[1]*pik[1] + pik[2]*pik[2] + pik[3]*pik[3]);
    const float mji = sji * (1.f / H_);
    const float rji = rsqrtf(qji * (1.f / H_) - mji * mji + 1e-5f);
    const float mik = sik * (1.f / H_);
    const float rik = rsqrtf(qik * (1.f / H_) - mik * mik + 1e-5f);
    const float eo0 = sE[eg4 + i][t0], eo1 = sE[eg4 + i][t0 + 1];
    const float eo2 = sE[eg4 + i][t0 + 2], eo3 = sE[eg4 + i][t0 + 3];
    ushort4 pkji, pkik;
    pkji.x = f2bf(eo0 + (pji[0] - mji) * rji * g4.x + lb4.x);
    pkji.y = f2bf(eo1 + (pji[1] - mji) * rji * g4.y + lb4.y);
    pkji.z = f2bf(eo2 + (pji[2] - mji) * rji * g4.z + lb4.z);
    pkji.w = f2bf(eo3 + (pji[3] - mji) * rji * g4.w + lb4.w);
    pkik.x = f2bf(eo0 + (pik[0] - mik) * rik * g4.x + lb4.x);
    pkik.y = f2bf(eo1 + (pik[1] - mik) * rik * g4.y + lb4.y);
    pkik.z = f2bf(eo2 + (pik[2] - mik) * rik * g4.z + lb4.z);
    pkik.w = f2bf(eo3 + (pik[3] - mik) * rik * g4.w + lb4.w);
    *(ushort4*)(e + eid * H_ + t0) = pkji;
    *(ushort4*)(eik_buf + eid * H_ + t0) = pkik;
  }
}

// per-node message gather: A1h[n] += sum_ji + sum_ik   [one wave per node]
__global__ __launch_bounds__(256) void k_gather(
    const u16* __restrict__ e, const u16* __restrict__ eik_buf,
    const int* __restrict__ slot_ji, const int* __restrict__ slot_ik,
    const int* __restrict__ offs_col, const int* __restrict__ offs_row,
    const int* __restrict__ rowp, const int* __restrict__ colp,
    const u16* __restrict__ A2h, const u16* __restrict__ A3h,
    float* __restrict__ A1h)
{
  const int w = threadIdx.x >> 6, lane = threadIdx.x & 63;
  const int n = blockIdx.x * 4 + w;
  const int t0 = lane * 2;
  float acc0 = 0.f, acc1 = 0.f;

  int s = offs_col[n], epos = offs_col[n + 1];
  for (int j = s; j < epos; ++j) {
    const int eid = slot_ji[j];
    const int r = rowp[eid];
    const unsigned ue = *(const unsigned*)(e + (size_t)eid * H_ + t0);
    const float sg0 = sigm(bf2f((u16)(ue & 0xffffu)));
    const float sg1 = sigm(bf2f((u16)(ue >> 16)));
    const float S = red64(sg0 + sg1);
    const float inv = 1.f / (S + 1e-6f);
    const unsigned ua = *(const unsigned*)(A2h + (size_t)r * H_ + t0);
    acc0 += bf2f((u16)(ua & 0xffffu)) * sg0 * inv;
    acc1 += bf2f((u16)(ua >> 16)) * sg1 * inv;
  }
  s = offs_row[n]; epos = offs_row[n + 1];
  for (int j = s; j < epos; ++j) {
    const int eid = slot_ik[j];
    const int c = colp[eid];
    const unsigned ue = *(const unsigned*)(eik_buf + (size_t)eid * H_ + t0);
    const float sg0 = sigm(bf2f((u16)(ue & 0xffffu)));
    const float sg1 = sigm(bf2f((u16)(ue >> 16)));
    const float S = red64(sg0 + sg1);
    const float inv = 1.f / (S + 1e-6f);
    const unsigned ua = *(const unsigned*)(A3h + (size_t)c * H_ + t0);
    acc0 += bf2f((u16)(ua & 0xffffu)) * sg0 * inv;
    acc1 += bf2f((u16)(ua >> 16)) * sg1 * inv;
  }
  float2 a = *(float2*)(A1h + (size_t)n * H_ + t0);
  a.x += acc0; a.y += acc1;
  *(float2*)(A1h + (size_t)n * H_ + t0) = a;
}

// ---------------- atomic fallback (round-2 exact) ----------------

__global__ __launch_bounds__(512) void k_layer_edge_atomic(
    u16* __restrict__ e,
    const int* __restrict__ rowp, const int* __restrict__ colp,
    const float* __restrict__ Bw0, const float* __restrict__ Bb0,
    const u16* __restrict__ A2h, const u16* __restrict__ A3h,
    const u16* __restrict__ B2h, const u16* __restrict__ B3h,
    const float* __restrict__ lng, const float* __restrict__ lnb,
    float* __restrict__ A1h)
{
  __shared__ float sE[TILE][132];
  const int tid = threadIdx.x;
  const int eg = tid >> 5, og = tid & 31;
  const int eg4 = eg * 4, t0 = og * 4;
  const size_t base = (size_t)blockIdx.x * TILE;
#pragma unroll
  for (int p = 0; p < 4; ++p) {
    const int fid = tid + p * 512;
    const int edge = fid >> 5, c4 = fid & 31;
    const ushort4 u = *(const ushort4*)(e + (base + edge) * H_ + c4 * 4);
    sE[edge][c4 * 4]     = bf2f(u.x);
    sE[edge][c4 * 4 + 1] = bf2f(u.y);
    sE[edge][c4 * 4 + 2] = bf2f(u.z);
    sE[edge][c4 * 4 + 3] = bf2f(u.w);
  }
  __syncthreads();

  const float4 bb = *(const float4*)(Bb0 + t0);
  float b1e[4][4];
#pragma unroll
  for (int i = 0; i < 4; ++i) { b1e[i][0] = bb.x; b1e[i][1] = bb.y; b1e[i][2] = bb.z; b1e[i][3] = bb.w; }
#pragma unroll 4
  for (int k = 0; k < H_; ++k) {
    const float4 wv = *(const float4*)(Bw0 + (size_t)k * H_ + t0);
    const float x0 = sE[eg4][k], x1 = sE[eg4 + 1][k], x2 = sE[eg4 + 2][k], x3 = sE[eg4 + 3][k];
    FMA16(b1e, x0, x1, x2, x3, wv)
  }

  const float4 g4  = *(const float4*)(lng + t0);
  const float4 lb4 = *(const float4*)(lnb + t0);
#pragma unroll 1
  for (int i = 0; i < 4; ++i) {
    const size_t eid = base + eg4 + i;
    const int r = rowp[eid], c = colp[eid];
    const ushort4 ub2r = *(const ushort4*)(B2h + (size_t)r * H_ + t0);
    const ushort4 ub3c = *(const ushort4*)(B3h + (size_t)c * H_ + t0);
    const ushort4 ub2c = *(const ushort4*)(B2h + (size_t)c * H_ + t0);
    const ushort4 ub3r = *(const ushort4*)(B3h + (size_t)r * H_ + t0);
    const ushort4 ua2r = *(const ushort4*)(A2h + (size_t)r * H_ + t0);
    const ushort4 ua3c = *(const ushort4*)(A3h + (size_t)c * H_ + t0);
    float pji[4], pik[4];
    pji[0] = fmaxf(b1e[i][0] + bf2f(ub2r.x) + bf2f(ub3c.x), 0.f);
    pji[1] = fmaxf(b1e[i][1] + bf2f(ub2r.y) + bf2f(ub3c.y), 0.f);
    pji[2] = fmaxf(b1e[i][2] + bf2f(ub2r.z) + bf2f(ub3c.z), 0.f);
    pji[3] = fmaxf(b1e[i][3] + bf2f(ub2r.w) + bf2f(ub3c.w), 0.f);
    pik[0] = fmaxf(b1e[i][0] + bf2f(ub2c.x) + bf2f(ub3r.x), 0.f);
    pik[1] = fmaxf(b1e[i][1] + bf2f(ub2c.y) + bf2f(ub3r.y), 0.f);
    pik[2] = fmaxf(b1e[i][2] + bf2f(ub2c.z) + bf2f(ub3r.z), 0.f);
    pik[3] = fmaxf(b1e[i][3] + bf2f(ub2c.w) + bf2f(ub3r.w), 0.f);
    const float sji = red32(pji[0] + pji[1] + pji[2] + pji[3]);
    const float qji = red32(pji[0]*pji[0] + pji[1]*pji[1] + pji[2]*pji[2] + pji[3]*pji[3]);
    const float sik = red32(pik[0] + pik[1] + pik[2] + pik[3]);
    const float qik = red32(pik[0]*pik[0] + pik[1]*pik[1] + pik[2]*pik[2] + pik[3]*pik[3]);
    const float mji = sji * (1.f / H_);
    const float rji = rsqrtf(qji * (1.f / H_) - mji * mji + 1e-5f);
    const float mik = sik * (1.f / H_);
    const float rik = rsqrtf(qik * (1.f / H_) - mik * mik + 1e-5f);
    const float eo0 = sE[eg4 + i][t0], eo1 = sE[eg4 + i][t0 + 1];
    const float eo2 = sE[eg4 + i][t0 + 2], eo3 = sE[eg4 + i][t0 + 3];
    float eji[4], eik[4];
    eji[0] = eo0 + (pji[0] - mji) * rji * g4.x + lb4.x;
    eji[1] = eo1 + (pji[1] - mji) * rji * g4.y + lb4.y;
    eji[2] = eo2 + (pji[2] - mji) * rji * g4.z + lb4.z;
    eji[3] = eo3 + (pji[3] - mji) * rji * g4.w + lb4.w;
    eik[0] = eo0 + (pik[0] - mik) * rik * g4.x + lb4.x;
    eik[1] = eo1 + (pik[1] - mik) * rik * g4.y + lb4.y;
    eik[2] = eo2 + (pik[2] - mik) * rik * g4.z + lb4.z;
    eik[3] = eo3 + (pik[3] - mik) * rik * g4.w + lb4.w;
    const float sgji0 = sigm(eji[0]), sgji1 = sigm(eji[1]), sgji2 = sigm(eji[2]), sgji3 = sigm(eji[3]);
    const float sgik0 = sigm(eik[0]), sgik1 = sigm(eik[1]), sgik2 = sigm(eik[2]), sgik3 = sigm(eik[3]);
    const float Sji = red32(sgji0 + sgji1 + sgji2 + sgji3);
    const float Sik = red32(sgik0 + sgik1 + sgik2 + sgik3);
    const float iji = 1.f / (Sji + 1e-6f);
    const float iik = 1.f / (Sik + 1e-6f);
    float* accc = A1h + (size_t)c * H_ + t0;
    float* accr = A1h + (size_t)r * H_ + t0;
    atomicAdd(accc + 0, bf2f(ua2r.x) * sgji0 * iji);
    atomicAdd(accc + 1, bf2f(ua2r.y) * sgji1 * iji);
    atomicAdd(accc + 2, bf2f(ua2r.z) * sgji2 * iji);
    atomicAdd(accc + 3, bf2f(ua2r.w) * sgji3 * iji);
    atomicAdd(accr + 0, bf2f(ua3c.x) * sgik0 * iik);
    atomicAdd(accr + 1, bf2f(ua3c.y) * sgik1 * iik);
    atomicAdd(accr + 2, bf2f(ua3c.z) * sgik2 * iik);
    atomicAdd(accr + 3, bf2f(ua3c.w) * sgik3 * iik);
    ushort4 pk;
    pk.x = f2bf(eji[0]); pk.y = f2bf(eji[1]); pk.z = f2bf(eji[2]); pk.w = f2bf(eji[3]);
    *(ushort4*)(e + eid * H_ + t0) = pk;
  }
}

// ---------------- node update + scorer ----------------

__global__ __launch_bounds__(256) void k_node_update(
    float* __restrict__ h, const float* __restrict__ A1h,
    const float* __restrict__ g, const float* __restrict__ b)
{
  const int w = threadIdx.x >> 6, lane = threadIdx.x & 63;
  const size_t node = (size_t)blockIdx.x * 4 + w;
  const int t0 = lane * 2;
  const float2 a = *(const float2*)(A1h + node * H_ + t0);
  const float u0 = fmaxf(a.x, 0.f);
  const float u1 = fmaxf(a.y, 0.f);
  const float sm = red64(u0 + u1);
  const float sq = red64(u0 * u0 + u1 * u1);
  const float mean = sm * (1.f / H_);
  const float rs = rsqrtf(sq * (1.f / H_) - mean * mean + 1e-5f);
  float2 hv = *(float2*)(h + node * H_ + t0);
  hv.x += (u0 - mean) * rs * g[t0] + b[t0];
  hv.y += (u1 - mean) * rs * g[t0 + 1] + b[t0 + 1];
  *(float2*)(h + node * H_ + t0) = hv;
}

__global__ __launch_bounds__(512) void k_score(
    const u16* __restrict__ e, const int* __restrict__ rowp, const int* __restrict__ colp,
    const float* __restrict__ h,
    const float* __restrict__ s1w, const float* __restrict__ s1b,
    const float* __restrict__ s2w, const float* __restrict__ s2b,
    float* __restrict__ out)
{
  __shared__ float sA[TILE][132];
  const int tid = threadIdx.x;
  const int eg = tid >> 5, og = tid & 31;
  const int eg4 = eg * 4, t0 = og * 4;
  const size_t base = (size_t)blockIdx.x * TILE;
  float accm[4][4] = {{0.f}};

#pragma unroll 1
  for (int qq = 0; qq < 3; ++qq) {
    __syncthreads();
#pragma unroll
    for (int p = 0; p < 4; ++p) {
      const int fid = tid + p * 512;
      const int edge = fid >> 5, c4 = fid & 31;
      if (qq == 2) {
        const ushort4 u = *(const ushort4*)(e + (base + edge) * H_ + c4 * 4);
        sA[edge][c4 * 4]     = bf2f(u.x);
        sA[edge][c4 * 4 + 1] = bf2f(u.y);
        sA[edge][c4 * 4 + 2] = bf2f(u.z);
        sA[edge][c4 * 4 + 3] = bf2f(u.w);
      } else {
        const int n = (qq == 0) ? rowp[base + edge] : colp[base + edge];
        const float4 v = *(const float4*)(h + (size_t)n * H_ + c4 * 4);
        *(float4*)(&sA[edge][c4 * 4]) = v;
      }
    }
    __syncthreads();
    const float* W = s1w + (size_t)qq * H_ * H_;
#pragma unroll 4
    for (int k = 0; k < H_; ++k) {
      const float4 wv = *(const float4*)(W + (size_t)k * H_ + t0);
      const float x0 = sA[eg4][k], x1 = sA[eg4 + 1][k], x2 = sA[eg4 + 2][k], x3 = sA[eg4 + 3][k];
      FMA16(accm, x0, x1, x2, x3, wv)
    }
  }

  const float4 sb = *(const float4*)(s1b + t0);
  const float4 w2 = *(const float4*)(s2w + t0);
  const float b2 = s2b[0];
#pragma unroll
  for (int i = 0; i < 4; ++i) {
    float p = fmaxf(accm[i][0] + sb.x, 0.f) * w2.x
            + fmaxf(accm[i][1] + sb.y, 0.f) * w2.y
            + fmaxf(accm[i][2] + sb.z, 0.f) * w2.z
            + fmaxf(accm[i][3] + sb.w, 0.f) * w2.w;
    p = red32(p);
    if (og == 0) out[base + eg4 + i] = p + b2;
  }
}

extern "C" void kernel_launch(void* const* d_in, const int* in_sizes, int n_in,
                              void* d_out, int out_size, void* d_ws, size_t ws_size,
                              hipStream_t stream) {
  const float* x    = (const float*)d_in[0];
  const float* ea   = (const float*)d_in[1];
  const int*   eidx = (const int*)d_in[2];
  const float* W11w = (const float*)d_in[3];
  const float* W11b = (const float*)d_in[4];
  const float* W12w = (const float*)d_in[5];
  const float* W12b = (const float*)d_in[6];
  const float* W21w = (const float*)d_in[7];
  const float* W21b = (const float*)d_in[8];
  const float* W22w = (const float*)d_in[9];
  const float* W22b = (const float*)d_in[10];
  const float* ln1g = (const float*)d_in[11];
  const float* ln1b = (const float*)d_in[12];
  const float* ln2g = (const float*)d_in[13];
  const float* ln2b = (const float*)d_in[14];
  const float* Aw   = (const float*)d_in[15];
  const float* Ab   = (const float*)d_in[16];
  const float* Bw   = (const float*)d_in[17];
  const float* Bb   = (const float*)d_in[18];
  const float* lnhg = (const float*)d_in[19];
  const float* lnhb = (const float*)d_in[20];
  const float* lneg = (const float*)d_in[21];
  const float* lneb = (const float*)d_in[22];
  const float* s1w  = (const float*)d_in[23];
  const float* s1b  = (const float*)d_in[24];
  const float* s2w  = (const float*)d_in[25];
  const float* s2b  = (const float*)d_in[26];
  float* out = (float*)d_out;

  k_sentinel<<<(out_size + 255) / 256, 256, 0, stream>>>(out, out_size);

  const size_t need_base   = 307200000;   // atomic path
  const size_t need_sorted = 519424000;   // sorted path (+eik, slots, offs)
  if (ws_size < need_base) return;        // sentinel (3e30) signals this

  char* wsb = (char*)d_ws;
  u16*   e   = (u16*)wsb;                        // [NE][128] bf16   204.8 MB
  float* h   = (float*)(wsb + 204800000);        // [NN][128] f32     25.6 MB
  float* A1h = (float*)(wsb + 230400000);        // [NN][128] f32     25.6 MB
  u16*   A2h = (u16*)(wsb + 256000000);          // [NN][128] bf16    12.8 MB
  u16*   A3h = (u16*)(wsb + 268800000);
  u16*   B2h = (u16*)(wsb + 281600000);
  u16*   B3h = (u16*)(wsb + 294400000);
  // sorted-path extras
  u16*   eik      = (u16*)(wsb + 307200000);     // [NE][128] bf16   204.8 MB
  int*   slot_ji  = (int*)(wsb + 512000000);     // [NE]               3.2 MB
  int*   slot_ik  = (int*)(wsb + 515200000);
  int*   offs_col = (int*)(wsb + 518400000);     // [NN+1]
  int*   offs_row = (int*)(wsb + 518656000);
  int*   cur_col  = (int*)(wsb + 518912000);     // counts, then fill cursors
  int*   cur_row  = (int*)(wsb + 519168000);

  const int* rowp = eidx;
  const int* colp = eidx + NE;
  const bool sorted = (ws_size >= need_sorted);

  k_node_enc<<<NN / 4, 256, 0, stream>>>(x, W11w, W11b, W12w, W12b, ln1g, ln1b, h);
  k_edge_enc<<<NE / TILE, 512, 0, stream>>>(ea, W21w, W21b, W22w, W22b, ln2g, ln2b, e);

  if (sorted) {
    hipMemsetAsync(cur_col, 0, (size_t)NN * sizeof(int), stream);
    hipMemsetAsync(cur_row, 0, (size_t)NN * sizeof(int), stream);
    k_count<<<(NE + 255) / 256, 256, 0, stream>>>(rowp, colp, cur_row, cur_col);
    k_scan2<<<2, 1024, 0, stream>>>(cur_col, offs_col, cur_row, offs_row, NN);
    k_copy_cur<<<(NN + 255) / 256, 256, 0, stream>>>(offs_col, offs_row, cur_col, cur_row);
    k_fill<<<(NE + 255) / 256, 256, 0, stream>>>(rowp, colp, cur_col, cur_row, slot_ji, slot_ik);
  }

  for (int l = 0; l < 3; ++l) {
    k_node_mats<<<(NN + TILE - 1) / TILE, 512, 0, stream>>>(h, Aw, Ab, Bw, Bb, l,
                                                            A1h, A2h, A3h, B2h, B3h);
    if (sorted) {
      k_layer_edge_s<<<NE / TILE, 512, 0, stream>>>(e, eik, rowp, colp,
          Bw + ((size_t)l * 3 + 0) * H_ * H_, Bb + ((size_t)l * 3 + 0) * H_,
          B2h, B3h, lneg + (size_t)l * H_, lneb + (size_t)l * H_);
      k_gather<<<NN / 4, 256, 0, stream>>>(e, eik, slot_ji, slot_ik, offs_col, offs_row,
                                           rowp, colp, A2h, A3h, A1h);
    } else {
      k_layer_edge_atomic<<<NE / TILE, 512, 0, stream>>>(e, rowp, colp,
          Bw + ((size_t)l * 3 + 0) * H_ * H_, Bb + ((size_t)l * 3 + 0) * H_,
          A2h, A3h, B2h, B3h, lneg + (size_t)l * H_, lneb + (size_t)l * H_, A1h);
    }
    k_node_update<<<NN / 4, 256, 0, stream>>>(h, A1h,
        lnhg + (size_t)l * H_, lnhb + (size_t)l * H_);
  }
  k_score<<<NE / TILE, 512, 0, stream>>>(e, rowp, colp, h, s1w, s1b, s2w, s2b, out);
}

// Round 4
// 5396.884 us; speedup vs baseline: 2.0880x; 2.0874x over previous
//
#include <hip/hip_runtime.h>
#include <math.h>

#define H_ 128
#define NN 50000
#define NE 800000
#define TILE 64

typedef unsigned short u16;

__device__ __forceinline__ float red32(float v) {
  v += __shfl_xor(v, 1);
  v += __shfl_xor(v, 2);
  v += __shfl_xor(v, 4);
  v += __shfl_xor(v, 8);
  v += __shfl_xor(v, 16);
  return v;
}
__device__ __forceinline__ float red64(float v) { v = red32(v); v += __shfl_xor(v, 32); return v; }
__device__ __forceinline__ float sigm(float x) { return 1.0f / (1.0f + __expf(-x)); }
__device__ __forceinline__ float bf2f(u16 s) { return __uint_as_float(((unsigned)s) << 16); }
__device__ __forceinline__ u16 f2bf(float f) {
  unsigned u = __float_as_uint(f);
  return (u16)((u + 0x7FFFu + ((u >> 16) & 1u)) >> 16);
}

#define FMA16(acc, x0, x1, x2, x3, wv) \
  acc[0][0] = fmaf(x0, wv.x, acc[0][0]); acc[0][1] = fmaf(x0, wv.y, acc[0][1]); \
  acc[0][2] = fmaf(x0, wv.z, acc[0][2]); acc[0][3] = fmaf(x0, wv.w, acc[0][3]); \
  acc[1][0] = fmaf(x1, wv.x, acc[1][0]); acc[1][1] = fmaf(x1, wv.y, acc[1][1]); \
  acc[1][2] = fmaf(x1, wv.z, acc[1][2]); acc[1][3] = fmaf(x1, wv.w, acc[1][3]); \
  acc[2][0] = fmaf(x2, wv.x, acc[2][0]); acc[2][1] = fmaf(x2, wv.y, acc[2][1]); \
  acc[2][2] = fmaf(x2, wv.z, acc[2][2]); acc[2][3] = fmaf(x2, wv.w, acc[2][3]); \
  acc[3][0] = fmaf(x3, wv.x, acc[3][0]); acc[3][1] = fmaf(x3, wv.y, acc[3][1]); \
  acc[3][2] = fmaf(x3, wv.z, acc[3][2]); acc[3][3] = fmaf(x3, wv.w, acc[3][3]);

__global__ void k_sentinel(float* __restrict__ out, int n) {
  int i = blockIdx.x * 256 + threadIdx.x;
  if (i < n) out[i] = 3.0e30f;
}

// ---------------- sort machinery (once per call) ----------------

__global__ void k_count(const int* __restrict__ rowp, const int* __restrict__ colp,
                        int* __restrict__ cnt_row, int* __restrict__ cnt_col) {
  int i = blockIdx.x * 256 + threadIdx.x;
  if (i < NE) {
    atomicAdd(&cnt_col[colp[i]], 1);
    atomicAdd(&cnt_row[rowp[i]], 1);
  }
}

__global__ __launch_bounds__(1024) void k_scan2(
    const int* __restrict__ c0, int* __restrict__ o0,
    const int* __restrict__ c1, int* __restrict__ o1, int n)
{
  const int* c = blockIdx.x ? c1 : c0;
  int* o = blockIdx.x ? o1 : o0;
  __shared__ int warpsum[16];
  const int tid = threadIdx.x;
  int carry = 0;
  for (int basei = 0; basei < n; basei += 1024) {
    const int vidx = basei + tid;
    const int v = (vidx < n) ? c[vidx] : 0;
    int s = v;
#pragma unroll
    for (int d = 1; d < 64; d <<= 1) {
      int t = __shfl_up(s, d);
      if ((tid & 63) >= d) s += t;
    }
    if ((tid & 63) == 63) warpsum[tid >> 6] = s;
    __syncthreads();
    if (tid < 16) {
      int ws = warpsum[tid];
#pragma unroll
      for (int d = 1; d < 16; d <<= 1) {
        int t = __shfl_up(ws, d);
        if (tid >= d) ws += t;
      }
      warpsum[tid] = ws;
    }
    __syncthreads();
    const int wave = tid >> 6;
    const int prefix = (wave == 0 ? 0 : warpsum[wave - 1]) + carry;
    if (vidx < n) o[vidx] = s - v + prefix;
    carry += warpsum[15];
    __syncthreads();
  }
  if (tid == 0) o[n] = carry;
}

__global__ void k_copy_cur(const int* __restrict__ oc, const int* __restrict__ orr,
                           int* __restrict__ cc, int* __restrict__ cr) {
  int i = blockIdx.x * 256 + threadIdx.x;
  if (i < NN) { cc[i] = oc[i]; cr[i] = orr[i]; }
}

__global__ void k_fill(const int* __restrict__ rowp, const int* __restrict__ colp,
                       int* __restrict__ cur_col, int* __restrict__ cur_row,
                       int* __restrict__ slot_ji, int* __restrict__ slot_ik) {
  int i = blockIdx.x * 256 + threadIdx.x;
  if (i < NE) {
    int p = atomicAdd(&cur_col[colp[i]], 1);
    slot_ji[p] = i;
    int q = atomicAdd(&cur_row[rowp[i]], 1);
    slot_ik[q] = i;
  }
}

// ---------------- encoders ----------------

__global__ __launch_bounds__(256) void k_node_enc(
    const float* __restrict__ x,
    const float* __restrict__ W11, const float* __restrict__ b11,
    const float* __restrict__ W12, const float* __restrict__ b12,
    const float* __restrict__ g1, const float* __restrict__ be1,
    float* __restrict__ h)
{
  __shared__ float sx[4][64];
  __shared__ float sv[4][130];
  const int w = threadIdx.x >> 6, lane = threadIdx.x & 63;
  const int node = blockIdx.x * 4 + w;
  sx[w][lane] = x[(size_t)node * 64 + lane];
  __syncthreads();
  const int t0 = lane * 2;
  float a0 = b11[t0], a1 = b11[t0 + 1];
#pragma unroll 8
  for (int k = 0; k < 64; ++k) {
    const float xk = sx[w][k];
    const float2 ww = *(const float2*)(W11 + (size_t)k * H_ + t0);
    a0 = fmaf(xk, ww.x, a0);
    a1 = fmaf(xk, ww.y, a1);
  }
  a0 = fmaxf(a0, 0.f); a1 = fmaxf(a1, 0.f);
  const float s = red64(a0 + a1);
  const float q = red64(a0 * a0 + a1 * a1);
  const float mean = s * (1.f / H_);
  const float rs = rsqrtf(q * (1.f / H_) - mean * mean + 1e-5f);
  sv[w][t0]     = (a0 - mean) * rs * g1[t0]     + be1[t0];
  sv[w][t0 + 1] = (a1 - mean) * rs * g1[t0 + 1] + be1[t0 + 1];
  __syncthreads();
  float c0 = b12[t0], c1 = b12[t0 + 1];
#pragma unroll 8
  for (int k = 0; k < H_; ++k) {
    const float vk = sv[w][k];
    const float2 ww = *(const float2*)(W12 + (size_t)k * H_ + t0);
    c0 = fmaf(vk, ww.x, c0);
    c1 = fmaf(vk, ww.y, c1);
  }
  h[(size_t)node * H_ + t0] = c0;
  h[(size_t)node * H_ + t0 + 1] = c1;
}

__global__ __launch_bounds__(512) void k_edge_enc(
    const float* __restrict__ ea,
    const float* __restrict__ W21, const float* __restrict__ b21,
    const float* __restrict__ W22, const float* __restrict__ b22,
    const float* __restrict__ g2, const float* __restrict__ be2,
    u16* __restrict__ e)
{
  __shared__ float sEA[TILE][36];
  __shared__ float sLN[TILE][130];
  const int tid = threadIdx.x;
  const int eg = tid >> 5, og = tid & 31;
  const int eg4 = eg * 4, t0 = og * 4;
  const size_t base = (size_t)blockIdx.x * TILE;
  {
    const int edge = tid >> 3, c4 = tid & 7;
    const float4 v = *(const float4*)(ea + (base + edge) * 32 + c4 * 4);
    *(float4*)(&sEA[edge][c4 * 4]) = v;
  }
  __syncthreads();

  const float4 b1 = *(const float4*)(b21 + t0);
  float a[4][4];
#pragma unroll
  for (int i = 0; i < 4; ++i) { a[i][0] = b1.x; a[i][1] = b1.y; a[i][2] = b1.z; a[i][3] = b1.w; }
#pragma unroll 8
  for (int k = 0; k < 32; ++k) {
    const float4 wv = *(const float4*)(W21 + (size_t)k * H_ + t0);
    const float x0 = sEA[eg4][k], x1 = sEA[eg4 + 1][k], x2 = sEA[eg4 + 2][k], x3 = sEA[eg4 + 3][k];
    FMA16(a, x0, x1, x2, x3, wv)
  }
  const float4 g4 = *(const float4*)(g2 + t0);
  const float4 bb = *(const float4*)(be2 + t0);
#pragma unroll
  for (int i = 0; i < 4; ++i) {
    const float r0 = fmaxf(a[i][0], 0.f), r1 = fmaxf(a[i][1], 0.f);
    const float r2 = fmaxf(a[i][2], 0.f), r3 = fmaxf(a[i][3], 0.f);
    const float s = red32(r0 + r1 + r2 + r3);
    const float q = red32(r0 * r0 + r1 * r1 + r2 * r2 + r3 * r3);
    const float mean = s * (1.f / H_);
    const float rs = rsqrtf(q * (1.f / H_) - mean * mean + 1e-5f);
    sLN[eg4 + i][t0]     = (r0 - mean) * rs * g4.x + bb.x;
    sLN[eg4 + i][t0 + 1] = (r1 - mean) * rs * g4.y + bb.y;
    sLN[eg4 + i][t0 + 2] = (r2 - mean) * rs * g4.z + bb.z;
    sLN[eg4 + i][t0 + 3] = (r3 - mean) * rs * g4.w + bb.w;
  }
  __syncthreads();

  const float4 b2 = *(const float4*)(b22 + t0);
  float c[4][4];
#pragma unroll
  for (int i = 0; i < 4; ++i) { c[i][0] = b2.x; c[i][1] = b2.y; c[i][2] = b2.z; c[i][3] = b2.w; }
#pragma unroll 4
  for (int k = 0; k < H_; ++k) {
    const float4 wv = *(const float4*)(W22 + (size_t)k * H_ + t0);
    const float x0 = sLN[eg4][k], x1 = sLN[eg4 + 1][k], x2 = sLN[eg4 + 2][k], x3 = sLN[eg4 + 3][k];
    FMA16(c, x0, x1, x2, x3, wv)
  }
#pragma unroll
  for (int i = 0; i < 4; ++i) {
    ushort4 pk;
    pk.x = f2bf(c[i][0]); pk.y = f2bf(c[i][1]); pk.z = f2bf(c[i][2]); pk.w = f2bf(c[i][3]);
    *(ushort4*)(e + (base + eg4 + i) * H_ + t0) = pk;
  }
}

// ---------------- per-layer node GEMMs ----------------

__global__ __launch_bounds__(512) void k_node_mats(
    const float* __restrict__ h,
    const float* __restrict__ Aw, const float* __restrict__ Ab,
    const float* __restrict__ Bw, const float* __restrict__ Bb,
    int l,
    float* __restrict__ A1h, u16* __restrict__ A2h, u16* __restrict__ A3h,
    u16* __restrict__ B2h, u16* __restrict__ B3h)
{
  __shared__ float sA[TILE][132];
  const int tid = threadIdx.x;
  const int eg = tid >> 5, og = tid & 31;
  const int eg4 = eg * 4, t0 = og * 4;
  const size_t base = (size_t)blockIdx.x * TILE;
#pragma unroll
  for (int p = 0; p < 4; ++p) {
    const int fid = tid + p * 512;
    const int r = fid >> 5, c4 = fid & 31;
    const float4 v = *(const float4*)(h + (base + r) * H_ + c4 * 4);
    *(float4*)(&sA[r][c4 * 4]) = v;
  }
  __syncthreads();

  const float* Wm[5]; const float* bm[5];
  Wm[0] = Aw + ((size_t)l * 3 + 0) * H_ * H_; bm[0] = Ab + ((size_t)l * 3 + 0) * H_;
  Wm[1] = Aw + ((size_t)l * 3 + 1) * H_ * H_; bm[1] = Ab + ((size_t)l * 3 + 1) * H_;
  Wm[2] = Aw + ((size_t)l * 3 + 2) * H_ * H_; bm[2] = Ab + ((size_t)l * 3 + 2) * H_;
  Wm[3] = Bw + ((size_t)l * 3 + 1) * H_ * H_; bm[3] = Bb + ((size_t)l * 3 + 1) * H_;
  Wm[4] = Bw + ((size_t)l * 3 + 2) * H_ * H_; bm[4] = Bb + ((size_t)l * 3 + 2) * H_;
  u16* om[5] = {0, A2h, A3h, B2h, B3h};

#pragma unroll 1
  for (int m = 0; m < 5; ++m) {
    const float4 bi = *(const float4*)(bm[m] + t0);
    float acc[4][4];
#pragma unroll
    for (int i = 0; i < 4; ++i) { acc[i][0] = bi.x; acc[i][1] = bi.y; acc[i][2] = bi.z; acc[i][3] = bi.w; }
    const float* W = Wm[m];
#pragma unroll 4
    for (int k = 0; k < H_; ++k) {
      const float4 wv = *(const float4*)(W + (size_t)k * H_ + t0);
      const float x0 = sA[eg4][k], x1 = sA[eg4 + 1][k], x2 = sA[eg4 + 2][k], x3 = sA[eg4 + 3][k];
      FMA16(acc, x0, x1, x2, x3, wv)
    }
#pragma unroll
    for (int i = 0; i < 4; ++i) {
      const size_t n = base + eg4 + i;
      if (n < (size_t)NN) {
        if (m == 0) {
          *(float4*)(A1h + n * H_ + t0) = make_float4(acc[i][0], acc[i][1], acc[i][2], acc[i][3]);
        } else {
          ushort4 pk;
          pk.x = f2bf(acc[i][0]); pk.y = f2bf(acc[i][1]); pk.z = f2bf(acc[i][2]); pk.w = f2bf(acc[i][3]);
          *(ushort4*)(om[m] + n * H_ + t0) = pk;
        }
      }
    }
  }
}

// ---------------- gated edge layer, sorted two-pass (no big-buffer, few atomics) ----

// Pass 1 (row-sorted): B1e GEMM, e <- e_ji (in place), segment-reduce m_ik by row.
__global__ __launch_bounds__(512) void k_layer_edge2(
    u16* __restrict__ e,
    const int* __restrict__ slot_ik,
    const int* __restrict__ rowp, const int* __restrict__ colp,
    const float* __restrict__ Bw0, const float* __restrict__ Bb0,
    const u16* __restrict__ A3h,
    const u16* __restrict__ B2h, const u16* __restrict__ B3h,
    const float* __restrict__ lng, const float* __restrict__ lnb,
    float* __restrict__ A1h)
{
  __shared__ float sE[TILE][132];      // e-tile for GEMM, then reused as message acc
  __shared__ int sEid[TILE];
  __shared__ int sRow[TILE];
  __shared__ int sCol[TILE];
  const int tid = threadIdx.x;
  const int eg = tid >> 5, og = tid & 31;
  const int eg4 = eg * 4, t0 = og * 4;
  const size_t base = (size_t)blockIdx.x * TILE;

  if (tid < TILE) {
    const int eid = slot_ik[base + tid];
    sEid[tid] = eid;
    sRow[tid] = rowp[eid];
    sCol[tid] = colp[eid];
  }
  __syncthreads();
#pragma unroll
  for (int p = 0; p < 4; ++p) {
    const int fid = tid + p * 512;
    const int j = fid >> 5, c4 = fid & 31;
    const ushort4 u = *(const ushort4*)(e + (size_t)sEid[j] * H_ + c4 * 4);
    sE[j][c4 * 4]     = bf2f(u.x);
    sE[j][c4 * 4 + 1] = bf2f(u.y);
    sE[j][c4 * 4 + 2] = bf2f(u.z);
    sE[j][c4 * 4 + 3] = bf2f(u.w);
  }
  __syncthreads();

  const float4 bb = *(const float4*)(Bb0 + t0);
  float b1e[4][4];
#pragma unroll
  for (int i = 0; i < 4; ++i) { b1e[i][0] = bb.x; b1e[i][1] = bb.y; b1e[i][2] = bb.z; b1e[i][3] = bb.w; }
#pragma unroll 4
  for (int k = 0; k < H_; ++k) {
    const float4 wv = *(const float4*)(Bw0 + (size_t)k * H_ + t0);
    const float x0 = sE[eg4][k], x1 = sE[eg4 + 1][k], x2 = sE[eg4 + 2][k], x3 = sE[eg4 + 3][k];
    FMA16(b1e, x0, x1, x2, x3, wv)
  }

  const float4 g4  = *(const float4*)(lng + t0);
  const float4 lb4 = *(const float4*)(lnb + t0);
#pragma unroll 1
  for (int i = 0; i < 4; ++i) {
    const int j = eg4 + i;
    const int eid = sEid[j];
    const int r = sRow[j], c = sCol[j];
    const ushort4 ub2r = *(const ushort4*)(B2h + (size_t)r * H_ + t0);
    const ushort4 ub3c = *(const ushort4*)(B3h + (size_t)c * H_ + t0);
    const ushort4 ub2c = *(const ushort4*)(B2h + (size_t)c * H_ + t0);
    const ushort4 ub3r = *(const ushort4*)(B3h + (size_t)r * H_ + t0);
    const ushort4 ua3c = *(const ushort4*)(A3h + (size_t)c * H_ + t0);
    float pji[4], pik[4];
    pji[0] = fmaxf(b1e[i][0] + bf2f(ub2r.x) + bf2f(ub3c.x), 0.f);
    pji[1] = fmaxf(b1e[i][1] + bf2f(ub2r.y) + bf2f(ub3c.y), 0.f);
    pji[2] = fmaxf(b1e[i][2] + bf2f(ub2r.z) + bf2f(ub3c.z), 0.f);
    pji[3] = fmaxf(b1e[i][3] + bf2f(ub2r.w) + bf2f(ub3c.w), 0.f);
    pik[0] = fmaxf(b1e[i][0] + bf2f(ub2c.x) + bf2f(ub3r.x), 0.f);
    pik[1] = fmaxf(b1e[i][1] + bf2f(ub2c.y) + bf2f(ub3r.y), 0.f);
    pik[2] = fmaxf(b1e[i][2] + bf2f(ub2c.z) + bf2f(ub3r.z), 0.f);
    pik[3] = fmaxf(b1e[i][3] + bf2f(ub2c.w) + bf2f(ub3r.w), 0.f);
    const float sji = red32(pji[0] + pji[1] + pji[2] + pji[3]);
    const float qji = red32(pji[0]*pji[0] + pji[1]*pji[1] + pji[2]*pji[2] + pji[3]*pji[3]);
    const float sik = red32(pik[0] + pik[1] + pik[2] + pik[3]);
    const float qik = red32(pik[0]*pik[0] + pik[1]*pik[1] + pik[2]*pik[2] + pik[3]*pik[3]);
    const float mji = sji * (1.f / H_);
    const float rji = rsqrtf(qji * (1.f / H_) - mji * mji + 1e-5f);
    const float mik = sik * (1.f / H_);
    const float rik = rsqrtf(qik * (1.f / H_) - mik * mik + 1e-5f);
    // read e_old BEFORE overwriting this LDS row with messages
    const float eo0 = sE[j][t0], eo1 = sE[j][t0 + 1];
    const float eo2 = sE[j][t0 + 2], eo3 = sE[j][t0 + 3];
    // e_ji -> global e (in place; this block is the only reader/writer of row eid)
    ushort4 pkji;
    pkji.x = f2bf(eo0 + (pji[0] - mji) * rji * g4.x + lb4.x);
    pkji.y = f2bf(eo1 + (pji[1] - mji) * rji * g4.y + lb4.y);
    pkji.z = f2bf(eo2 + (pji[2] - mji) * rji * g4.z + lb4.z);
    pkji.w = f2bf(eo3 + (pji[3] - mji) * rji * g4.w + lb4.w);
    *(ushort4*)(e + (size_t)eid * H_ + t0) = pkji;
    // e_ik -> sigmoid -> normalized ik message into LDS (reuse sE row)
    const float e0 = eo0 + (pik[0] - mik) * rik * g4.x + lb4.x;
    const float e1 = eo1 + (pik[1] - mik) * rik * g4.y + lb4.y;
    const float e2 = eo2 + (pik[2] - mik) * rik * g4.z + lb4.z;
    const float e3 = eo3 + (pik[3] - mik) * rik * g4.w + lb4.w;
    const float sg0 = sigm(e0), sg1 = sigm(e1), sg2 = sigm(e2), sg3 = sigm(e3);
    const float S = red32(sg0 + sg1 + sg2 + sg3);
    const float inv = 1.f / (S + 1e-6f);
    sE[j][t0]     = bf2f(ua3c.x) * sg0 * inv;
    sE[j][t0 + 1] = bf2f(ua3c.y) * sg1 * inv;
    sE[j][t0 + 2] = bf2f(ua3c.z) * sg2 * inv;
    sE[j][t0 + 3] = bf2f(ua3c.w) * sg3 * inv;
  }
  __syncthreads();

  // segmented reduction by destination row (sRow non-decreasing)
  const int f = tid & 127;
  const int sgrp = tid >> 7;
  int seg = 0, j = 0;
  while (j < TILE) {
    const int r = sRow[j];
    int jend = j + 1;
    while (jend < TILE && sRow[jend] == r) ++jend;
    if ((seg & 3) == sgrp) {
      float s = 0.f;
      for (int k2 = j; k2 < jend; ++k2) s += sE[k2][f];
      atomicAdd(&A1h[(size_t)r * H_ + f], s);
    }
    ++seg; j = jend;
  }
}

// Pass 2 (col-sorted): read updated e (= e_ji), segment-reduce m_ji by col.
__global__ __launch_bounds__(512) void k_gather_ji(
    const u16* __restrict__ e,
    const int* __restrict__ slot_ji,
    const int* __restrict__ rowp, const int* __restrict__ colp,
    const u16* __restrict__ A2h,
    float* __restrict__ A1h)
{
  __shared__ float sM[TILE][132];
  __shared__ int sEid[TILE];
  __shared__ int sRow[TILE];
  __shared__ int sCol[TILE];
  const int tid = threadIdx.x;
  const int eg = tid >> 5, og = tid & 31;
  const int eg4 = eg * 4, t0 = og * 4;
  const size_t base = (size_t)blockIdx.x * TILE;

  if (tid < TILE) {
    const int eid = slot_ji[base + tid];
    sEid[tid] = eid;
    sRow[tid] = rowp[eid];
    sCol[tid] = colp[eid];
  }
  __syncthreads();

#pragma unroll 1
  for (int i = 0; i < 4; ++i) {
    const int j = eg4 + i;
    const int eid = sEid[j];
    const int r = sRow[j];
    const ushort4 ue = *(const ushort4*)(e + (size_t)eid * H_ + t0);
    const float sg0 = sigm(bf2f(ue.x));
    const float sg1 = sigm(bf2f(ue.y));
    const float sg2 = sigm(bf2f(ue.z));
    const float sg3 = sigm(bf2f(ue.w));
    const float S = red32(sg0 + sg1 + sg2 + sg3);
    const float inv = 1.f / (S + 1e-6f);
    const ushort4 ua = *(const ushort4*)(A2h + (size_t)r * H_ + t0);
    sM[j][t0]     = bf2f(ua.x) * sg0 * inv;
    sM[j][t0 + 1] = bf2f(ua.y) * sg1 * inv;
    sM[j][t0 + 2] = bf2f(ua.z) * sg2 * inv;
    sM[j][t0 + 3] = bf2f(ua.w) * sg3 * inv;
  }
  __syncthreads();

  const int f = tid & 127;
  const int sgrp = tid >> 7;
  int seg = 0, j = 0;
  while (j < TILE) {
    const int c = sCol[j];
    int jend = j + 1;
    while (jend < TILE && sCol[jend] == c) ++jend;
    if ((seg & 3) == sgrp) {
      float s = 0.f;
      for (int k2 = j; k2 < jend; ++k2) s += sM[k2][f];
      atomicAdd(&A1h[(size_t)c * H_ + f], s);
    }
    ++seg; j = jend;
  }
}

// ---------------- atomic fallback (round-2 exact) ----------------

__global__ __launch_bounds__(512) void k_layer_edge_atomic(
    u16* __restrict__ e,
    const int* __restrict__ rowp, const int* __restrict__ colp,
    const float* __restrict__ Bw0, const float* __restrict__ Bb0,
    const u16* __restrict__ A2h, const u16* __restrict__ A3h,
    const u16* __restrict__ B2h, const u16* __restrict__ B3h,
    const float* __restrict__ lng, const float* __restrict__ lnb,
    float* __restrict__ A1h)
{
  __shared__ float sE[TILE][132];
  const int tid = threadIdx.x;
  const int eg = tid >> 5, og = tid & 31;
  const int eg4 = eg * 4, t0 = og * 4;
  const size_t base = (size_t)blockIdx.x * TILE;
#pragma unroll
  for (int p = 0; p < 4; ++p) {
    const int fid = tid + p * 512;
    const int edge = fid >> 5, c4 = fid & 31;
    const ushort4 u = *(const ushort4*)(e + (base + edge) * H_ + c4 * 4);
    sE[edge][c4 * 4]     = bf2f(u.x);
    sE[edge][c4 * 4 + 1] = bf2f(u.y);
    sE[edge][c4 * 4 + 2] = bf2f(u.z);
    sE[edge][c4 * 4 + 3] = bf2f(u.w);
  }
  __syncthreads();

  const float4 bb = *(const float4*)(Bb0 + t0);
  float b1e[4][4];
#pragma unroll
  for (int i = 0; i < 4; ++i) { b1e[i][0] = bb.x; b1e[i][1] = bb.y; b1e[i][2] = bb.z; b1e[i][3] = bb.w; }
#pragma unroll 4
  for (int k = 0; k < H_; ++k) {
    const float4 wv = *(const float4*)(Bw0 + (size_t)k * H_ + t0);
    const float x0 = sE[eg4][k], x1 = sE[eg4 + 1][k], x2 = sE[eg4 + 2][k], x3 = sE[eg4 + 3][k];
    FMA16(b1e, x0, x1, x2, x3, wv)
  }

  const float4 g4  = *(const float4*)(lng + t0);
  const float4 lb4 = *(const float4*)(lnb + t0);
#pragma unroll 1
  for (int i = 0; i < 4; ++i) {
    const size_t eid = base + eg4 + i;
    const int r = rowp[eid], c = colp[eid];
    const ushort4 ub2r = *(const ushort4*)(B2h + (size_t)r * H_ + t0);
    const ushort4 ub3c = *(const ushort4*)(B3h + (size_t)c * H_ + t0);
    const ushort4 ub2c = *(const ushort4*)(B2h + (size_t)c * H_ + t0);
    const ushort4 ub3r = *(const ushort4*)(B3h + (size_t)r * H_ + t0);
    const ushort4 ua2r = *(const ushort4*)(A2h + (size_t)r * H_ + t0);
    const ushort4 ua3c = *(const ushort4*)(A3h + (size_t)c * H_ + t0);
    float pji[4], pik[4];
    pji[0] = fmaxf(b1e[i][0] + bf2f(ub2r.x) + bf2f(ub3c.x), 0.f);
    pji[1] = fmaxf(b1e[i][1] + bf2f(ub2r.y) + bf2f(ub3c.y), 0.f);
    pji[2] = fmaxf(b1e[i][2] + bf2f(ub2r.z) + bf2f(ub3c.z), 0.f);
    pji[3] = fmaxf(b1e[i][3] + bf2f(ub2r.w) + bf2f(ub3c.w), 0.f);
    pik[0] = fmaxf(b1e[i][0] + bf2f(ub2c.x) + bf2f(ub3r.x), 0.f);
    pik[1] = fmaxf(b1e[i][1] + bf2f(ub2c.y) + bf2f(ub3r.y), 0.f);
    pik[2] = fmaxf(b1e[i][2] + bf2f(ub2c.z) + bf2f(ub3r.z), 0.f);
    pik[3] = fmaxf(b1e[i][3] + bf2f(ub2c.w) + bf2f(ub3r.w), 0.f);
    const float sji = red32(pji[0] + pji[1] + pji[2] + pji[3]);
    const float qji = red32(pji[0]*pji[0] + pji[1]*pji[1] + pji[2]*pji[2] + pji[3]*pji[3]);
    const float sik = red32(pik[0] + pik[1] + pik[2] + pik[3]);
    const float qik = red32(pik[0]*pik[0] + pik[1]*pik[1] + pik[2]*pik[2] + pik[3]*pik[3]);
    const float mji = sji * (1.f / H_);
    const float rji = rsqrtf(qji * (1.f / H_) - mji * mji + 1e-5f);
    const float mik = sik * (1.f / H_);
    const float rik = rsqrtf(qik * (1.f / H_) - mik * mik + 1e-5f);
    const float eo0 = sE[eg4 + i][t0], eo1 = sE[eg4 + i][t0 + 1];
    const float eo2 = sE[eg4 + i][t0 + 2], eo3 = sE[eg4 + i][t0 + 3];
    float eji[4], eik[4];
    eji[0] = eo0 + (pji[0] - mji) * rji * g4.x + lb4.x;
    eji[1] = eo1 + (pji[1] - mji) * rji * g4.y + lb4.y;
    eji[2] = eo2 + (pji[2] - mji) * rji * g4.z + lb4.z;
    eji[3] = eo3 + (pji[3] - mji) * rji * g4.w + lb4.w;
    eik[0] = eo0 + (pik[0] - mik) * rik * g4.x + lb4.x;
    eik[1] = eo1 + (pik[1] - mik) * rik * g4.y + lb4.y;
    eik[2] = eo2 + (pik[2] - mik) * rik * g4.z + lb4.z;
    eik[3] = eo3 + (pik[3] - mik) * rik * g4.w + lb4.w;
    const float sgji0 = sigm(eji[0]), sgji1 = sigm(eji[1]), sgji2 = sigm(eji[2]), sgji3 = sigm(eji[3]);
    const float sgik0 = sigm(eik[0]), sgik1 = sigm(eik[1]), sgik2 = sigm(eik[2]), sgik3 = sigm(eik[3]);
    const float Sji = red32(sgji0 + sgji1 + sgji2 + sgji3);
    const float Sik = red32(sgik0 + sgik1 + sgik2 + sgik3);
    const float iji = 1.f / (Sji + 1e-6f);
    const float iik = 1.f / (Sik + 1e-6f);
    float* accc = A1h + (size_t)c * H_ + t0;
    float* accr = A1h + (size_t)r * H_ + t0;
    atomicAdd(accc + 0, bf2f(ua2r.x) * sgji0 * iji);
    atomicAdd(accc + 1, bf2f(ua2r.y) * sgji1 * iji);
    atomicAdd(accc + 2, bf2f(ua2r.z) * sgji2 * iji);
    atomicAdd(accc + 3, bf2f(ua2r.w) * sgji3 * iji);
    atomicAdd(accr + 0, bf2f(ua3c.x) * sgik0 * iik);
    atomicAdd(accr + 1, bf2f(ua3c.y) * sgik1 * iik);
    atomicAdd(accr + 2, bf2f(ua3c.z) * sgik2 * iik);
    atomicAdd(accr + 3, bf2f(ua3c.w) * sgik3 * iik);
    ushort4 pk;
    pk.x = f2bf(eji[0]); pk.y = f2bf(eji[1]); pk.z = f2bf(eji[2]); pk.w = f2bf(eji[3]);
    *(ushort4*)(e + eid * H_ + t0) = pk;
  }
}

// ---------------- node update + scorer ----------------

__global__ __launch_bounds__(256) void k_node_update(
    float* __restrict__ h, const float* __restrict__ A1h,
    const float* __restrict__ g, const float* __restrict__ b)
{
  const int w = threadIdx.x >> 6, lane = threadIdx.x & 63;
  const size_t node = (size_t)blockIdx.x * 4 + w;
  const int t0 = lane * 2;
  const float2 a = *(const float2*)(A1h + node * H_ + t0);
  const float u0 = fmaxf(a.x, 0.f);
  const float u1 = fmaxf(a.y, 0.f);
  const float sm = red64(u0 + u1);
  const float sq = red64(u0 * u0 + u1 * u1);
  const float mean = sm * (1.f / H_);
  const float rs = rsqrtf(sq * (1.f / H_) - mean * mean + 1e-5f);
  float2 hv = *(float2*)(h + node * H_ + t0);
  hv.x += (u0 - mean) * rs * g[t0] + b[t0];
  hv.y += (u1 - mean) * rs * g[t0 + 1] + b[t0 + 1];
  *(float2*)(h + node * H_ + t0) = hv;
}

__global__ __launch_bounds__(512) void k_score(
    const u16* __restrict__ e, const int* __restrict__ rowp, const int* __restrict__ colp,
    const float* __restrict__ h,
    const float* __restrict__ s1w, const float* __restrict__ s1b,
    const float* __restrict__ s2w, const float* __restrict__ s2b,
    float* __restrict__ out)
{
  __shared__ float sA[TILE][132];
  const int tid = threadIdx.x;
  const int eg = tid >> 5, og = tid & 31;
  const int eg4 = eg * 4, t0 = og * 4;
  const size_t base = (size_t)blockIdx.x * TILE;
  float accm[4][4] = {{0.f}};

#pragma unroll 1
  for (int qq = 0; qq < 3; ++qq) {
    __syncthreads();
#pragma unroll
    for (int p = 0; p < 4; ++p) {
      const int fid = tid + p * 512;
      const int edge = fid >> 5, c4 = fid & 31;
      if (qq == 2) {
        const ushort4 u = *(const ushort4*)(e + (base + edge) * H_ + c4 * 4);
        sA[edge][c4 * 4]     = bf2f(u.x);
        sA[edge][c4 * 4 + 1] = bf2f(u.y);
        sA[edge][c4 * 4 + 2] = bf2f(u.z);
        sA[edge][c4 * 4 + 3] = bf2f(u.w);
      } else {
        const int n = (qq == 0) ? rowp[base + edge] : colp[base + edge];
        const float4 v = *(const float4*)(h + (size_t)n * H_ + c4 * 4);
        *(float4*)(&sA[edge][c4 * 4]) = v;
      }
    }
    __syncthreads();
    const float* W = s1w + (size_t)qq * H_ * H_;
#pragma unroll 4
    for (int k = 0; k < H_; ++k) {
      const float4 wv = *(const float4*)(W + (size_t)k * H_ + t0);
      const float x0 = sA[eg4][k], x1 = sA[eg4 + 1][k], x2 = sA[eg4 + 2][k], x3 = sA[eg4 + 3][k];
      FMA16(accm, x0, x1, x2, x3, wv)
    }
  }

  const float4 sb = *(const float4*)(s1b + t0);
  const float4 w2 = *(const float4*)(s2w + t0);
  const float b2 = s2b[0];
#pragma unroll
  for (int i = 0; i < 4; ++i) {
    float p = fmaxf(accm[i][0] + sb.x, 0.f) * w2.x
            + fmaxf(accm[i][1] + sb.y, 0.f) * w2.y
            + fmaxf(accm[i][2] + sb.z, 0.f) * w2.z
            + fmaxf(accm[i][3] + sb.w, 0.f) * w2.w;
    p = red32(p);
    if (og == 0) out[base + eg4 + i] = p + b2;
  }
}

extern "C" void kernel_launch(void* const* d_in, const int* in_sizes, int n_in,
                              void* d_out, int out_size, void* d_ws, size_t ws_size,
                              hipStream_t stream) {
  const float* x    = (const float*)d_in[0];
  const float* ea   = (const float*)d_in[1];
  const int*   eidx = (const int*)d_in[2];
  const float* W11w = (const float*)d_in[3];
  const float* W11b = (const float*)d_in[4];
  const float* W12w = (const float*)d_in[5];
  const float* W12b = (const float*)d_in[6];
  const float* W21w = (const float*)d_in[7];
  const float* W21b = (const float*)d_in[8];
  const float* W22w = (const float*)d_in[9];
  const float* W22b = (const float*)d_in[10];
  const float* ln1g = (const float*)d_in[11];
  const float* ln1b = (const float*)d_in[12];
  const float* ln2g = (const float*)d_in[13];
  const float* ln2b = (const float*)d_in[14];
  const float* Aw   = (const float*)d_in[15];
  const float* Ab   = (const float*)d_in[16];
  const float* Bw   = (const float*)d_in[17];
  const float* Bb   = (const float*)d_in[18];
  const float* lnhg = (const float*)d_in[19];
  const float* lnhb = (const float*)d_in[20];
  const float* lneg = (const float*)d_in[21];
  const float* lneb = (const float*)d_in[22];
  const float* s1w  = (const float*)d_in[23];
  const float* s1b  = (const float*)d_in[24];
  const float* s2w  = (const float*)d_in[25];
  const float* s2b  = (const float*)d_in[26];
  float* out = (float*)d_out;

  k_sentinel<<<(out_size + 255) / 256, 256, 0, stream>>>(out, out_size);

  const size_t need_base   = 307200000;   // atomic fallback
  const size_t need_sorted = 314624000;   // + slots (6.4M) + offs/cur (1.0M)
  if (ws_size < need_base) return;        // sentinel (3e30) signals this

  char* wsb = (char*)d_ws;
  u16*   e   = (u16*)wsb;                        // [NE][128] bf16   204.8 MB
  float* h   = (float*)(wsb + 204800000);        // [NN][128] f32     25.6 MB
  float* A1h = (float*)(wsb + 230400000);        // [NN][128] f32     25.6 MB
  u16*   A2h = (u16*)(wsb + 256000000);          // [NN][128] bf16    12.8 MB
  u16*   A3h = (u16*)(wsb + 268800000);
  u16*   B2h = (u16*)(wsb + 281600000);
  u16*   B3h = (u16*)(wsb + 294400000);
  int*   slot_ji  = (int*)(wsb + 307200000);     // [NE] col-sorted    3.2 MB
  int*   slot_ik  = (int*)(wsb + 310400000);     // [NE] row-sorted    3.2 MB
  int*   offs_col = (int*)(wsb + 313600000);     // [NN+1]
  int*   offs_row = (int*)(wsb + 313856000);
  int*   cur_col  = (int*)(wsb + 314112000);
  int*   cur_row  = (int*)(wsb + 314368000);

  const int* rowp = eidx;
  const int* colp = eidx + NE;
  const bool sorted = (ws_size >= need_sorted);

  k_node_enc<<<NN / 4, 256, 0, stream>>>(x, W11w, W11b, W12w, W12b, ln1g, ln1b, h);
  k_edge_enc<<<NE / TILE, 512, 0, stream>>>(ea, W21w, W21b, W22w, W22b, ln2g, ln2b, e);

  if (sorted) {
    hipMemsetAsync(cur_col, 0, (size_t)NN * sizeof(int), stream);
    hipMemsetAsync(cur_row, 0, (size_t)NN * sizeof(int), stream);
    k_count<<<(NE + 255) / 256, 256, 0, stream>>>(rowp, colp, cur_row, cur_col);
    k_scan2<<<2, 1024, 0, stream>>>(cur_col, offs_col, cur_row, offs_row, NN);
    k_copy_cur<<<(NN + 255) / 256, 256, 0, stream>>>(offs_col, offs_row, cur_col, cur_row);
    k_fill<<<(NE + 255) / 256, 256, 0, stream>>>(rowp, colp, cur_col, cur_row, slot_ji, slot_ik);
  }

  for (int l = 0; l < 3; ++l) {
    k_node_mats<<<(NN + TILE - 1) / TILE, 512, 0, stream>>>(h, Aw, Ab, Bw, Bb, l,
                                                            A1h, A2h, A3h, B2h, B3h);
    if (sorted) {
      k_layer_edge2<<<NE / TILE, 512, 0, stream>>>(e, slot_ik, rowp, colp,
          Bw + ((size_t)l * 3 + 0) * H_ * H_, Bb + ((size_t)l * 3 + 0) * H_,
          A3h, B2h, B3h, lneg + (size_t)l * H_, lneb + (size_t)l * H_, A1h);
      k_gather_ji<<<NE / TILE, 512, 0, stream>>>(e, slot_ji, rowp, colp, A2h, A1h);
    } else {
      k_layer_edge_atomic<<<NE / TILE, 512, 0, stream>>>(e, rowp, colp,
          Bw + ((size_t)l * 3 + 0) * H_ * H_, Bb + ((size_t)l * 3 + 0) * H_,
          A2h, A3h, B2h, B3h, lneg + (size_t)l * H_, lneb + (size_t)l * H_, A1h);
    }
    k_node_update<<<NN / 4, 256, 0, stream>>>(h, A1h,
        lnhg + (size_t)l * H_, lnhb + (size_t)l * H_);
  }
  k_score<<<NE / TILE, 512, 0, stream>>>(e, rowp, colp, h, s1w, s1b, s2w, s2b, out);
}

// Round 5
// 4211.882 us; speedup vs baseline: 2.6754x; 1.2813x over previous
//
#include <hip/hip_runtime.h>
#include <math.h>

#define H_ 128
#define NN 50000
#define NE 800000
#define TILE 64

typedef unsigned short u16;
typedef __attribute__((ext_vector_type(8))) __bf16 bf16x8;
typedef __attribute__((ext_vector_type(4))) float f32x4;

__device__ __forceinline__ float red32(float v) {
  v += __shfl_xor(v, 1);
  v += __shfl_xor(v, 2);
  v += __shfl_xor(v, 4);
  v += __shfl_xor(v, 8);
  v += __shfl_xor(v, 16);
  return v;
}
__device__ __forceinline__ float red64(float v) { v = red32(v); v += __shfl_xor(v, 32); return v; }
__device__ __forceinline__ float sigm(float x) { return 1.0f / (1.0f + __expf(-x)); }
__device__ __forceinline__ float bf2f(u16 s) { return __uint_as_float(((unsigned)s) << 16); }
__device__ __forceinline__ u16 f2bf(float f) {
  unsigned u = __float_as_uint(f);
  return (u16)((u + 0x7FFFu + ((u >> 16) & 1u)) >> 16);
}

#define FMA16(acc, x0, x1, x2, x3, wv) \
  acc[0][0] = fmaf(x0, wv.x, acc[0][0]); acc[0][1] = fmaf(x0, wv.y, acc[0][1]); \
  acc[0][2] = fmaf(x0, wv.z, acc[0][2]); acc[0][3] = fmaf(x0, wv.w, acc[0][3]); \
  acc[1][0] = fmaf(x1, wv.x, acc[1][0]); acc[1][1] = fmaf(x1, wv.y, acc[1][1]); \
  acc[1][2] = fmaf(x1, wv.z, acc[1][2]); acc[1][3] = fmaf(x1, wv.w, acc[1][3]); \
  acc[2][0] = fmaf(x2, wv.x, acc[2][0]); acc[2][1] = fmaf(x2, wv.y, acc[2][1]); \
  acc[2][2] = fmaf(x2, wv.z, acc[2][2]); acc[2][3] = fmaf(x2, wv.w, acc[2][3]); \
  acc[3][0] = fmaf(x3, wv.x, acc[3][0]); acc[3][1] = fmaf(x3, wv.y, acc[3][1]); \
  acc[3][2] = fmaf(x3, wv.z, acc[3][2]); acc[3][3] = fmaf(x3, wv.w, acc[3][3]);

__global__ void k_sentinel(float* __restrict__ out, int n) {
  int i = blockIdx.x * 256 + threadIdx.x;
  if (i < n) out[i] = 3.0e30f;
}

// ---------------- sort machinery (once per call) ----------------

__global__ void k_count(const int* __restrict__ rowp, const int* __restrict__ colp,
                        int* __restrict__ cnt_row, int* __restrict__ cnt_col) {
  int i = blockIdx.x * 256 + threadIdx.x;
  if (i < NE) {
    atomicAdd(&cnt_col[colp[i]], 1);
    atomicAdd(&cnt_row[rowp[i]], 1);
  }
}

__global__ __launch_bounds__(1024) void k_scan2(
    const int* __restrict__ c0, int* __restrict__ o0,
    const int* __restrict__ c1, int* __restrict__ o1, int n)
{
  const int* c = blockIdx.x ? c1 : c0;
  int* o = blockIdx.x ? o1 : o0;
  __shared__ int warpsum[16];
  const int tid = threadIdx.x;
  int carry = 0;
  for (int basei = 0; basei < n; basei += 1024) {
    const int vidx = basei + tid;
    const int v = (vidx < n) ? c[vidx] : 0;
    int s = v;
#pragma unroll
    for (int d = 1; d < 64; d <<= 1) {
      int t = __shfl_up(s, d);
      if ((tid & 63) >= d) s += t;
    }
    if ((tid & 63) == 63) warpsum[tid >> 6] = s;
    __syncthreads();
    if (tid < 16) {
      int ws = warpsum[tid];
#pragma unroll
      for (int d = 1; d < 16; d <<= 1) {
        int t = __shfl_up(ws, d);
        if (tid >= d) ws += t;
      }
      warpsum[tid] = ws;
    }
    __syncthreads();
    const int wave = tid >> 6;
    const int prefix = (wave == 0 ? 0 : warpsum[wave - 1]) + carry;
    if (vidx < n) o[vidx] = s - v + prefix;
    carry += warpsum[15];
    __syncthreads();
  }
  if (tid == 0) o[n] = carry;
}

__global__ void k_copy_cur(const int* __restrict__ oc, const int* __restrict__ orr,
                           int* __restrict__ cc, int* __restrict__ cr) {
  int i = blockIdx.x * 256 + threadIdx.x;
  if (i < NN) { cc[i] = oc[i]; cr[i] = orr[i]; }
}

__global__ void k_fill(const int* __restrict__ rowp, const int* __restrict__ colp,
                       int* __restrict__ cur_col, int* __restrict__ cur_row,
                       int* __restrict__ slot_ji, int* __restrict__ slot_ik) {
  int i = blockIdx.x * 256 + threadIdx.x;
  if (i < NE) {
    int p = atomicAdd(&cur_col[colp[i]], 1);
    slot_ji[p] = i;
    int q = atomicAdd(&cur_row[rowp[i]], 1);
    slot_ik[q] = i;
  }
}

// ---------------- bf16 prep for MFMA scorer ----------------

// pack s1w [384][128] f32 -> fragment-order bf16: packed[((t*8+nt)*64+l)*8+e]
//   = s1w[(t*32 + (l>>4)*8 + e)*128 + nt*16 + (l&15)]
__global__ void k_pack_s1w(const float* __restrict__ s1w, u16* __restrict__ packed) {
  int tid = blockIdx.x * 256 + threadIdx.x;
  if (tid < 49152) {
    const int e = tid & 7, l = (tid >> 3) & 63, nt = (tid >> 9) & 7, t = tid >> 12;
    const int k = t * 32 + (l >> 4) * 8 + e;
    const int n = nt * 16 + (l & 15);
    packed[tid] = f2bf(s1w[k * H_ + n]);
  }
}

__global__ void k_h2bf(const float* __restrict__ h, u16* __restrict__ h_bf) {
  const int i = blockIdx.x * 256 + threadIdx.x;   // NN*128/4 threads
  const float4 v = ((const float4*)h)[i];
  ushort4 p;
  p.x = f2bf(v.x); p.y = f2bf(v.y); p.z = f2bf(v.z); p.w = f2bf(v.w);
  ((ushort4*)h_bf)[i] = p;
}

// ---------------- encoders ----------------

__global__ __launch_bounds__(256) void k_node_enc(
    const float* __restrict__ x,
    const float* __restrict__ W11, const float* __restrict__ b11,
    const float* __restrict__ W12, const float* __restrict__ b12,
    const float* __restrict__ g1, const float* __restrict__ be1,
    float* __restrict__ h)
{
  __shared__ float sx[4][64];
  __shared__ float sv[4][130];
  const int w = threadIdx.x >> 6, lane = threadIdx.x & 63;
  const int node = blockIdx.x * 4 + w;
  sx[w][lane] = x[(size_t)node * 64 + lane];
  __syncthreads();
  const int t0 = lane * 2;
  float a0 = b11[t0], a1 = b11[t0 + 1];
#pragma unroll 8
  for (int k = 0; k < 64; ++k) {
    const float xk = sx[w][k];
    const float2 ww = *(const float2*)(W11 + (size_t)k * H_ + t0);
    a0 = fmaf(xk, ww.x, a0);
    a1 = fmaf(xk, ww.y, a1);
  }
  a0 = fmaxf(a0, 0.f); a1 = fmaxf(a1, 0.f);
  const float s = red64(a0 + a1);
  const float q = red64(a0 * a0 + a1 * a1);
  const float mean = s * (1.f / H_);
  const float rs = rsqrtf(q * (1.f / H_) - mean * mean + 1e-5f);
  sv[w][t0]     = (a0 - mean) * rs * g1[t0]     + be1[t0];
  sv[w][t0 + 1] = (a1 - mean) * rs * g1[t0 + 1] + be1[t0 + 1];
  __syncthreads();
  float c0 = b12[t0], c1 = b12[t0 + 1];
#pragma unroll 8
  for (int k = 0; k < H_; ++k) {
    const float vk = sv[w][k];
    const float2 ww = *(const float2*)(W12 + (size_t)k * H_ + t0);
    c0 = fmaf(vk, ww.x, c0);
    c1 = fmaf(vk, ww.y, c1);
  }
  h[(size_t)node * H_ + t0] = c0;
  h[(size_t)node * H_ + t0 + 1] = c1;
}

__global__ __launch_bounds__(512) void k_edge_enc(
    const float* __restrict__ ea,
    const float* __restrict__ W21, const float* __restrict__ b21,
    const float* __restrict__ W22, const float* __restrict__ b22,
    const float* __restrict__ g2, const float* __restrict__ be2,
    u16* __restrict__ e)
{
  __shared__ float sEA[TILE][36];
  __shared__ float sLN[TILE][130];
  const int tid = threadIdx.x;
  const int eg = tid >> 5, og = tid & 31;
  const int eg4 = eg * 4, t0 = og * 4;
  const size_t base = (size_t)blockIdx.x * TILE;
  {
    const int edge = tid >> 3, c4 = tid & 7;
    const float4 v = *(const float4*)(ea + (base + edge) * 32 + c4 * 4);
    *(float4*)(&sEA[edge][c4 * 4]) = v;
  }
  __syncthreads();

  const float4 b1 = *(const float4*)(b21 + t0);
  float a[4][4];
#pragma unroll
  for (int i = 0; i < 4; ++i) { a[i][0] = b1.x; a[i][1] = b1.y; a[i][2] = b1.z; a[i][3] = b1.w; }
#pragma unroll 8
  for (int k = 0; k < 32; ++k) {
    const float4 wv = *(const float4*)(W21 + (size_t)k * H_ + t0);
    const float x0 = sEA[eg4][k], x1 = sEA[eg4 + 1][k], x2 = sEA[eg4 + 2][k], x3 = sEA[eg4 + 3][k];
    FMA16(a, x0, x1, x2, x3, wv)
  }
  const float4 g4 = *(const float4*)(g2 + t0);
  const float4 bb = *(const float4*)(be2 + t0);
#pragma unroll
  for (int i = 0; i < 4; ++i) {
    const float r0 = fmaxf(a[i][0], 0.f), r1 = fmaxf(a[i][1], 0.f);
    const float r2 = fmaxf(a[i][2], 0.f), r3 = fmaxf(a[i][3], 0.f);
    const float s = red32(r0 + r1 + r2 + r3);
    const float q = red32(r0 * r0 + r1 * r1 + r2 * r2 + r3 * r3);
    const float mean = s * (1.f / H_);
    const float rs = rsqrtf(q * (1.f / H_) - mean * mean + 1e-5f);
    sLN[eg4 + i][t0]     = (r0 - mean) * rs * g4.x + bb.x;
    sLN[eg4 + i][t0 + 1] = (r1 - mean) * rs * g4.y + bb.y;
    sLN[eg4 + i][t0 + 2] = (r2 - mean) * rs * g4.z + bb.z;
    sLN[eg4 + i][t0 + 3] = (r3 - mean) * rs * g4.w + bb.w;
  }
  __syncthreads();

  const float4 b2 = *(const float4*)(b22 + t0);
  float c[4][4];
#pragma unroll
  for (int i = 0; i < 4; ++i) { c[i][0] = b2.x; c[i][1] = b2.y; c[i][2] = b2.z; c[i][3] = b2.w; }
#pragma unroll 4
  for (int k = 0; k < H_; ++k) {
    const float4 wv = *(const float4*)(W22 + (size_t)k * H_ + t0);
    const float x0 = sLN[eg4][k], x1 = sLN[eg4 + 1][k], x2 = sLN[eg4 + 2][k], x3 = sLN[eg4 + 3][k];
    FMA16(c, x0, x1, x2, x3, wv)
  }
#pragma unroll
  for (int i = 0; i < 4; ++i) {
    ushort4 pk;
    pk.x = f2bf(c[i][0]); pk.y = f2bf(c[i][1]); pk.z = f2bf(c[i][2]); pk.w = f2bf(c[i][3]);
    *(ushort4*)(e + (base + eg4 + i) * H_ + t0) = pk;
  }
}

// ---------------- per-layer node GEMMs ----------------

__global__ __launch_bounds__(512) void k_node_mats(
    const float* __restrict__ h,
    const float* __restrict__ Aw, const float* __restrict__ Ab,
    const float* __restrict__ Bw, const float* __restrict__ Bb,
    int l,
    float* __restrict__ A1h, u16* __restrict__ A2h, u16* __restrict__ A3h,
    u16* __restrict__ B2h, u16* __restrict__ B3h)
{
  __shared__ float sA[TILE][132];
  const int tid = threadIdx.x;
  const int eg = tid >> 5, og = tid & 31;
  const int eg4 = eg * 4, t0 = og * 4;
  const size_t base = (size_t)blockIdx.x * TILE;
#pragma unroll
  for (int p = 0; p < 4; ++p) {
    const int fid = tid + p * 512;
    const int r = fid >> 5, c4 = fid & 31;
    const float4 v = *(const float4*)(h + (base + r) * H_ + c4 * 4);
    *(float4*)(&sA[r][c4 * 4]) = v;
  }
  __syncthreads();

  const float* Wm[5]; const float* bm[5];
  Wm[0] = Aw + ((size_t)l * 3 + 0) * H_ * H_; bm[0] = Ab + ((size_t)l * 3 + 0) * H_;
  Wm[1] = Aw + ((size_t)l * 3 + 1) * H_ * H_; bm[1] = Ab + ((size_t)l * 3 + 1) * H_;
  Wm[2] = Aw + ((size_t)l * 3 + 2) * H_ * H_; bm[2] = Ab + ((size_t)l * 3 + 2) * H_;
  Wm[3] = Bw + ((size_t)l * 3 + 1) * H_ * H_; bm[3] = Bb + ((size_t)l * 3 + 1) * H_;
  Wm[4] = Bw + ((size_t)l * 3 + 2) * H_ * H_; bm[4] = Bb + ((size_t)l * 3 + 2) * H_;
  u16* om[5] = {0, A2h, A3h, B2h, B3h};

#pragma unroll 1
  for (int m = 0; m < 5; ++m) {
    const float4 bi = *(const float4*)(bm[m] + t0);
    float acc[4][4];
#pragma unroll
    for (int i = 0; i < 4; ++i) { acc[i][0] = bi.x; acc[i][1] = bi.y; acc[i][2] = bi.z; acc[i][3] = bi.w; }
    const float* W = Wm[m];
#pragma unroll 4
    for (int k = 0; k < H_; ++k) {
      const float4 wv = *(const float4*)(W + (size_t)k * H_ + t0);
      const float x0 = sA[eg4][k], x1 = sA[eg4 + 1][k], x2 = sA[eg4 + 2][k], x3 = sA[eg4 + 3][k];
      FMA16(acc, x0, x1, x2, x3, wv)
    }
#pragma unroll
    for (int i = 0; i < 4; ++i) {
      const size_t n = base + eg4 + i;
      if (n < (size_t)NN) {
        if (m == 0) {
          *(float4*)(A1h + n * H_ + t0) = make_float4(acc[i][0], acc[i][1], acc[i][2], acc[i][3]);
        } else {
          ushort4 pk;
          pk.x = f2bf(acc[i][0]); pk.y = f2bf(acc[i][1]); pk.z = f2bf(acc[i][2]); pk.w = f2bf(acc[i][3]);
          *(ushort4*)(om[m] + n * H_ + t0) = pk;
        }
      }
    }
  }
}

// ---------------- gated edge layer, sorted two-pass (no big-buffer, few atomics) ----

__global__ __launch_bounds__(512) void k_layer_edge2(
    u16* __restrict__ e,
    const int* __restrict__ slot_ik,
    const int* __restrict__ rowp, const int* __restrict__ colp,
    const float* __restrict__ Bw0, const float* __restrict__ Bb0,
    const u16* __restrict__ A3h,
    const u16* __restrict__ B2h, const u16* __restrict__ B3h,
    const float* __restrict__ lng, const float* __restrict__ lnb,
    float* __restrict__ A1h)
{
  __shared__ float sE[TILE][132];
  __shared__ int sEid[TILE];
  __shared__ int sRow[TILE];
  __shared__ int sCol[TILE];
  const int tid = threadIdx.x;
  const int eg = tid >> 5, og = tid & 31;
  const int eg4 = eg * 4, t0 = og * 4;
  const size_t base = (size_t)blockIdx.x * TILE;

  if (tid < TILE) {
    const int eid = slot_ik[base + tid];
    sEid[tid] = eid;
    sRow[tid] = rowp[eid];
    sCol[tid] = colp[eid];
  }
  __syncthreads();
#pragma unroll
  for (int p = 0; p < 4; ++p) {
    const int fid = tid + p * 512;
    const int j = fid >> 5, c4 = fid & 31;
    const ushort4 u = *(const ushort4*)(e + (size_t)sEid[j] * H_ + c4 * 4);
    sE[j][c4 * 4]     = bf2f(u.x);
    sE[j][c4 * 4 + 1] = bf2f(u.y);
    sE[j][c4 * 4 + 2] = bf2f(u.z);
    sE[j][c4 * 4 + 3] = bf2f(u.w);
  }
  __syncthreads();

  const float4 bb = *(const float4*)(Bb0 + t0);
  float b1e[4][4];
#pragma unroll
  for (int i = 0; i < 4; ++i) { b1e[i][0] = bb.x; b1e[i][1] = bb.y; b1e[i][2] = bb.z; b1e[i][3] = bb.w; }
#pragma unroll 4
  for (int k = 0; k < H_; ++k) {
    const float4 wv = *(const float4*)(Bw0 + (size_t)k * H_ + t0);
    const float x0 = sE[eg4][k], x1 = sE[eg4 + 1][k], x2 = sE[eg4 + 2][k], x3 = sE[eg4 + 3][k];
    FMA16(b1e, x0, x1, x2, x3, wv)
  }

  const float4 g4  = *(const float4*)(lng + t0);
  const float4 lb4 = *(const float4*)(lnb + t0);
#pragma unroll 1
  for (int i = 0; i < 4; ++i) {
    const int j = eg4 + i;
    const int eid = sEid[j];
    const int r = sRow[j], c = sCol[j];
    const ushort4 ub2r = *(const ushort4*)(B2h + (size_t)r * H_ + t0);
    const ushort4 ub3c = *(const ushort4*)(B3h + (size_t)c * H_ + t0);
    const ushort4 ub2c = *(const ushort4*)(B2h + (size_t)c * H_ + t0);
    const ushort4 ub3r = *(const ushort4*)(B3h + (size_t)r * H_ + t0);
    const ushort4 ua3c = *(const ushort4*)(A3h + (size_t)c * H_ + t0);
    float pji[4], pik[4];
    pji[0] = fmaxf(b1e[i][0] + bf2f(ub2r.x) + bf2f(ub3c.x), 0.f);
    pji[1] = fmaxf(b1e[i][1] + bf2f(ub2r.y) + bf2f(ub3c.y), 0.f);
    pji[2] = fmaxf(b1e[i][2] + bf2f(ub2r.z) + bf2f(ub3c.z), 0.f);
    pji[3] = fmaxf(b1e[i][3] + bf2f(ub2r.w) + bf2f(ub3c.w), 0.f);
    pik[0] = fmaxf(b1e[i][0] + bf2f(ub2c.x) + bf2f(ub3r.x), 0.f);
    pik[1] = fmaxf(b1e[i][1] + bf2f(ub2c.y) + bf2f(ub3r.y), 0.f);
    pik[2] = fmaxf(b1e[i][2] + bf2f(ub2c.z) + bf2f(ub3r.z), 0.f);
    pik[3] = fmaxf(b1e[i][3] + bf2f(ub2c.w) + bf2f(ub3r.w), 0.f);
    const float sji = red32(pji[0] + pji[1] + pji[2] + pji[3]);
    const float qji = red32(pji[0]*pji[0] + pji[1]*pji[1] + pji[2]*pji[2] + pji[3]*pji[3]);
    const float sik = red32(pik[0] + pik[1] + pik[2] + pik[3]);
    const float qik = red32(pik[0]*pik[0] + pik[1]*pik[1] + pik[2]*pik[2] + pik[3]*pik[3]);
    const float mji = sji * (1.f / H_);
    const float rji = rsqrtf(qji * (1.f / H_) - mji * mji + 1e-5f);
    const float mik = sik * (1.f / H_);
    const float rik = rsqrtf(qik * (1.f / H_) - mik * mik + 1e-5f);
    const float eo0 = sE[j][t0], eo1 = sE[j][t0 + 1];
    const float eo2 = sE[j][t0 + 2], eo3 = sE[j][t0 + 3];
    ushort4 pkji;
    pkji.x = f2bf(eo0 + (pji[0] - mji) * rji * g4.x + lb4.x);
    pkji.y = f2bf(eo1 + (pji[1] - mji) * rji * g4.y + lb4.y);
    pkji.z = f2bf(eo2 + (pji[2] - mji) * rji * g4.z + lb4.z);
    pkji.w = f2bf(eo3 + (pji[3] - mji) * rji * g4.w + lb4.w);
    *(ushort4*)(e + (size_t)eid * H_ + t0) = pkji;
    const float e0 = eo0 + (pik[0] - mik) * rik * g4.x + lb4.x;
    const float e1 = eo1 + (pik[1] - mik) * rik * g4.y + lb4.y;
    const float e2 = eo2 + (pik[2] - mik) * rik * g4.z + lb4.z;
    const float e3 = eo3 + (pik[3] - mik) * rik * g4.w + lb4.w;
    const float sg0 = sigm(e0), sg1 = sigm(e1), sg2 = sigm(e2), sg3 = sigm(e3);
    const float S = red32(sg0 + sg1 + sg2 + sg3);
    const float inv = 1.f / (S + 1e-6f);
    sE[j][t0]     = bf2f(ua3c.x) * sg0 * inv;
    sE[j][t0 + 1] = bf2f(ua3c.y) * sg1 * inv;
    sE[j][t0 + 2] = bf2f(ua3c.z) * sg2 * inv;
    sE[j][t0 + 3] = bf2f(ua3c.w) * sg3 * inv;
  }
  __syncthreads();

  const int f = tid & 127;
  const int sgrp = tid >> 7;
  int seg = 0, j = 0;
  while (j < TILE) {
    const int r = sRow[j];
    int jend = j + 1;
    while (jend < TILE && sRow[jend] == r) ++jend;
    if ((seg & 3) == sgrp) {
      float s = 0.f;
      for (int k2 = j; k2 < jend; ++k2) s += sE[k2][f];
      atomicAdd(&A1h[(size_t)r * H_ + f], s);
    }
    ++seg; j = jend;
  }
}

__global__ __launch_bounds__(512) void k_gather_ji(
    const u16* __restrict__ e,
    const int* __restrict__ slot_ji,
    const int* __restrict__ rowp, const int* __restrict__ colp,
    const u16* __restrict__ A2h,
    float* __restrict__ A1h)
{
  __shared__ float sM[TILE][132];
  __shared__ int sEid[TILE];
  __shared__ int sRow[TILE];
  __shared__ int sCol[TILE];
  const int tid = threadIdx.x;
  const int eg = tid >> 5, og = tid & 31;
  const int eg4 = eg * 4, t0 = og * 4;
  const size_t base = (size_t)blockIdx.x * TILE;

  if (tid < TILE) {
    const int eid = slot_ji[base + tid];
    sEid[tid] = eid;
    sRow[tid] = rowp[eid];
    sCol[tid] = colp[eid];
  }
  __syncthreads();

#pragma unroll 1
  for (int i = 0; i < 4; ++i) {
    const int j = eg4 + i;
    const int eid = sEid[j];
    const int r = sRow[j];
    const ushort4 ue = *(const ushort4*)(e + (size_t)eid * H_ + t0);
    const float sg0 = sigm(bf2f(ue.x));
    const float sg1 = sigm(bf2f(ue.y));
    const float sg2 = sigm(bf2f(ue.z));
    const float sg3 = sigm(bf2f(ue.w));
    const float S = red32(sg0 + sg1 + sg2 + sg3);
    const float inv = 1.f / (S + 1e-6f);
    const ushort4 ua = *(const ushort4*)(A2h + (size_t)r * H_ + t0);
    sM[j][t0]     = bf2f(ua.x) * sg0 * inv;
    sM[j][t0 + 1] = bf2f(ua.y) * sg1 * inv;
    sM[j][t0 + 2] = bf2f(ua.z) * sg2 * inv;
    sM[j][t0 + 3] = bf2f(ua.w) * sg3 * inv;
  }
  __syncthreads();

  const int f = tid & 127;
  const int sgrp = tid >> 7;
  int seg = 0, j = 0;
  while (j < TILE) {
    const int c = sCol[j];
    int jend = j + 1;
    while (jend < TILE && sCol[jend] == c) ++jend;
    if ((seg & 3) == sgrp) {
      float s = 0.f;
      for (int k2 = j; k2 < jend; ++k2) s += sM[k2][f];
      atomicAdd(&A1h[(size_t)c * H_ + f], s);
    }
    ++seg; j = jend;
  }
}

// ---------------- node update ----------------

__global__ __launch_bounds__(256) void k_node_update(
    float* __restrict__ h, const float* __restrict__ A1h,
    const float* __restrict__ g, const float* __restrict__ b)
{
  const int w = threadIdx.x >> 6, lane = threadIdx.x & 63;
  const size_t node = (size_t)blockIdx.x * 4 + w;
  const int t0 = lane * 2;
  const float2 a = *(const float2*)(A1h + node * H_ + t0);
  const float u0 = fmaxf(a.x, 0.f);
  const float u1 = fmaxf(a.y, 0.f);
  const float sm = red64(u0 + u1);
  const float sq = red64(u0 * u0 + u1 * u1);
  const float mean = sm * (1.f / H_);
  const float rs = rsqrtf(sq * (1.f / H_) - mean * mean + 1e-5f);
  float2 hv = *(float2*)(h + node * H_ + t0);
  hv.x += (u0 - mean) * rs * g[t0] + b[t0];
  hv.y += (u1 - mean) * rs * g[t0 + 1] + b[t0 + 1];
  *(float2*)(h + node * H_ + t0) = hv;
}

// ---------------- MFMA scorer ----------------
// 128 edges/block, 8 waves x 16 edges; K=384 in 12 steps of 32.
// A[m][k]: lane m16=l&15 -> edge row; k = 8*(l>>4)+e (assumed std layout)
// B[k][n]: from pre-packed fragment-order s1w (one 16B LDS read per frag)
// D[m][n]: verified col=l&15, row=(l>>4)*4+r
__global__ __launch_bounds__(512) void k_score_mfma(
    const u16* __restrict__ e, const int* __restrict__ rowp, const int* __restrict__ colp,
    const u16* __restrict__ h_bf, const u16* __restrict__ s1w_packed,
    const float* __restrict__ s1b, const float* __restrict__ s2w,
    const float* __restrict__ s2b, float* __restrict__ out)
{
  __shared__ u16 sB[8 * 64 * 8];   // 8 KB: one k-step of fragment-packed B
  const int tid = threadIdx.x;
  const int w = tid >> 6, lane = tid & 63;
  const int m16 = lane & 15, kg = lane >> 4;
  const size_t gbase = (size_t)blockIdx.x * 128;
  const int eidx = (int)gbase + w * 16 + m16;
  const int r_ = rowp[eidx], c_ = colp[eidx];
  const u16* srcA0 = h_bf + (size_t)r_ * H_;
  const u16* srcA1 = h_bf + (size_t)c_ * H_;
  const u16* srcA2 = e + (size_t)eidx * H_;

  f32x4 acc[8];
#pragma unroll
  for (int nt = 0; nt < 8; ++nt) { acc[nt][0] = 0.f; acc[nt][1] = 0.f; acc[nt][2] = 0.f; acc[nt][3] = 0.f; }

#pragma unroll 1
  for (int t = 0; t < 12; ++t) {
    __syncthreads();
    {
      const uint4* src = (const uint4*)(s1w_packed + (size_t)t * 4096);
      ((uint4*)sB)[tid] = src[tid];
    }
    __syncthreads();
    const u16* sa = (t < 4) ? srcA0 : (t < 8) ? srcA1 : srcA2;
    const int tt = t & 3;
    const bf16x8 a = *(const bf16x8*)(sa + tt * 32 + kg * 8);
#pragma unroll
    for (int nt = 0; nt < 8; ++nt) {
      const bf16x8 b = *(const bf16x8*)(sB + nt * 512 + lane * 8);
      acc[nt] = __builtin_amdgcn_mfma_f32_16x16x32_bf16(a, b, acc[nt], 0, 0, 0);
    }
  }

  float partial[4] = {0.f, 0.f, 0.f, 0.f};
#pragma unroll
  for (int nt = 0; nt < 8; ++nt) {
    const int c = nt * 16 + m16;
    const float sb1 = s1b[c];
    const float w2 = s2w[c];
#pragma unroll
    for (int r = 0; r < 4; ++r)
      partial[r] += fmaxf(acc[nt][r] + sb1, 0.f) * w2;
  }
  const float b2 = s2b[0];
#pragma unroll
  for (int r = 0; r < 4; ++r) {
    float v = partial[r];
    v += __shfl_xor(v, 1); v += __shfl_xor(v, 2);
    v += __shfl_xor(v, 4); v += __shfl_xor(v, 8);
    if (m16 == 0) out[gbase + w * 16 + kg * 4 + r] = v + b2;
  }
}

// ---------------- f32 scorer (ws fallback) ----------------

__global__ __launch_bounds__(512) void k_score(
    const u16* __restrict__ e, const int* __restrict__ rowp, const int* __restrict__ colp,
    const float* __restrict__ h,
    const float* __restrict__ s1w, const float* __restrict__ s1b,
    const float* __restrict__ s2w, const float* __restrict__ s2b,
    float* __restrict__ out)
{
  __shared__ float sA[TILE][132];
  const int tid = threadIdx.x;
  const int eg = tid >> 5, og = tid & 31;
  const int eg4 = eg * 4, t0 = og * 4;
  const size_t base = (size_t)blockIdx.x * TILE;
  float accm[4][4] = {{0.f}};

#pragma unroll 1
  for (int qq = 0; qq < 3; ++qq) {
    __syncthreads();
#pragma unroll
    for (int p = 0; p < 4; ++p) {
      const int fid = tid + p * 512;
      const int edge = fid >> 5, c4 = fid & 31;
      if (qq == 2) {
        const ushort4 u = *(const ushort4*)(e + (base + edge) * H_ + c4 * 4);
        sA[edge][c4 * 4]     = bf2f(u.x);
        sA[edge][c4 * 4 + 1] = bf2f(u.y);
        sA[edge][c4 * 4 + 2] = bf2f(u.z);
        sA[edge][c4 * 4 + 3] = bf2f(u.w);
      } else {
        const int n = (qq == 0) ? rowp[base + edge] : colp[base + edge];
        const float4 v = *(const float4*)(h + (size_t)n * H_ + c4 * 4);
        *(float4*)(&sA[edge][c4 * 4]) = v;
      }
    }
    __syncthreads();
    const float* W = s1w + (size_t)qq * H_ * H_;
#pragma unroll 4
    for (int k = 0; k < H_; ++k) {
      const float4 wv = *(const float4*)(W + (size_t)k * H_ + t0);
      const float x0 = sA[eg4][k], x1 = sA[eg4 + 1][k], x2 = sA[eg4 + 2][k], x3 = sA[eg4 + 3][k];
      FMA16(accm, x0, x1, x2, x3, wv)
    }
  }

  const float4 sb = *(const float4*)(s1b + t0);
  const float4 w2 = *(const float4*)(s2w + t0);
  const float b2 = s2b[0];
#pragma unroll
  for (int i = 0; i < 4; ++i) {
    float p = fmaxf(accm[i][0] + sb.x, 0.f) * w2.x
            + fmaxf(accm[i][1] + sb.y, 0.f) * w2.y
            + fmaxf(accm[i][2] + sb.z, 0.f) * w2.z
            + fmaxf(accm[i][3] + sb.w, 0.f) * w2.w;
    p = red32(p);
    if (og == 0) out[base + eg4 + i] = p + b2;
  }
}

extern "C" void kernel_launch(void* const* d_in, const int* in_sizes, int n_in,
                              void* d_out, int out_size, void* d_ws, size_t ws_size,
                              hipStream_t stream) {
  const float* x    = (const float*)d_in[0];
  const float* ea   = (const float*)d_in[1];
  const int*   eidx = (const int*)d_in[2];
  const float* W11w = (const float*)d_in[3];
  const float* W11b = (const float*)d_in[4];
  const float* W12w = (const float*)d_in[5];
  const float* W12b = (const float*)d_in[6];
  const float* W21w = (const float*)d_in[7];
  const float* W21b = (const float*)d_in[8];
  const float* W22w = (const float*)d_in[9];
  const float* W22b = (const float*)d_in[10];
  const float* ln1g = (const float*)d_in[11];
  const float* ln1b = (const float*)d_in[12];
  const float* ln2g = (const float*)d_in[13];
  const float* ln2b = (const float*)d_in[14];
  const float* Aw   = (const float*)d_in[15];
  const float* Ab   = (const float*)d_in[16];
  const float* Bw   = (const float*)d_in[17];
  const float* Bb   = (const float*)d_in[18];
  const float* lnhg = (const float*)d_in[19];
  const float* lnhb = (const float*)d_in[20];
  const float* lneg = (const float*)d_in[21];
  const float* lneb = (const float*)d_in[22];
  const float* s1w  = (const float*)d_in[23];
  const float* s1b  = (const float*)d_in[24];
  const float* s2w  = (const float*)d_in[25];
  const float* s2b  = (const float*)d_in[26];
  float* out = (float*)d_out;

  k_sentinel<<<(out_size + 255) / 256, 256, 0, stream>>>(out, out_size);

  const size_t need_base   = 307200000;   // atomic fallback
  const size_t need_sorted = 314624000;   // + slots + offs/cur (s1w_packed & h_bf overlay dead regions)
  if (ws_size < need_base) return;        // sentinel (3e30) signals this

  char* wsb = (char*)d_ws;
  u16*   e   = (u16*)wsb;                        // [NE][128] bf16   204.8 MB
  float* h   = (float*)(wsb + 204800000);        // [NN][128] f32     25.6 MB
  float* A1h = (float*)(wsb + 230400000);        // [NN][128] f32     25.6 MB
  u16*   A2h = (u16*)(wsb + 256000000);          // [NN][128] bf16    12.8 MB
  u16*   A3h = (u16*)(wsb + 268800000);
  u16*   B2h = (u16*)(wsb + 281600000);
  u16*   B3h = (u16*)(wsb + 294400000);
  int*   slot_ji  = (int*)(wsb + 307200000);     // [NE] col-sorted    3.2 MB
  int*   slot_ik  = (int*)(wsb + 310400000);     // [NE] row-sorted    3.2 MB
  int*   offs_col = (int*)(wsb + 313600000);     // [NN+1]
  int*   offs_row = (int*)(wsb + 313856000);
  int*   cur_col  = (int*)(wsb + 314112000);
  int*   cur_row  = (int*)(wsb + 314368000);
  // overlays (regions dead by the time these are written):
  u16*   h_bf       = (u16*)(wsb + 230400000);   // over A1h (dead after last node_update)
  u16*   s1w_packed = (u16*)(wsb + 314112000);   // over cur_col (dead after k_fill)

  const int* rowp = eidx;
  const int* colp = eidx + NE;
  const bool sorted = (ws_size >= need_sorted);

  k_node_enc<<<NN / 4, 256, 0, stream>>>(x, W11w, W11b, W12w, W12b, ln1g, ln1b, h);
  k_edge_enc<<<NE / TILE, 512, 0, stream>>>(ea, W21w, W21b, W22w, W22b, ln2g, ln2b, e);

  if (sorted) {
    hipMemsetAsync(cur_col, 0, (size_t)NN * sizeof(int), stream);
    hipMemsetAsync(cur_row, 0, (size_t)NN * sizeof(int), stream);
    k_count<<<(NE + 255) / 256, 256, 0, stream>>>(rowp, colp, cur_row, cur_col);
    k_scan2<<<2, 1024, 0, stream>>>(cur_col, offs_col, cur_row, offs_row, NN);
    k_copy_cur<<<(NN + 255) / 256, 256, 0, stream>>>(offs_col, offs_row, cur_col, cur_row);
    k_fill<<<(NE + 255) / 256, 256, 0, stream>>>(rowp, colp, cur_col, cur_row, slot_ji, slot_ik);
    k_pack_s1w<<<192, 256, 0, stream>>>(s1w, s1w_packed);   // overwrites cur_col (done with it)
  }

  for (int l = 0; l < 3; ++l) {
    k_node_mats<<<(NN + TILE - 1) / TILE, 512, 0, stream>>>(h, Aw, Ab, Bw, Bb, l,
                                                            A1h, A2h, A3h, B2h, B3h);
    if (sorted) {
      k_layer_edge2<<<NE / TILE, 512, 0, stream>>>(e, slot_ik, rowp, colp,
          Bw + ((size_t)l * 3 + 0) * H_ * H_, Bb + ((size_t)l * 3 + 0) * H_,
          A3h, B2h, B3h, lneg + (size_t)l * H_, lneb + (size_t)l * H_, A1h);
      k_gather_ji<<<NE / TILE, 512, 0, stream>>>(e, slot_ji, rowp, colp, A2h, A1h);
    } else {
      // (atomic fallback removed from flow only if sorted; keep behavior for small ws)
      k_layer_edge2<<<NE / TILE, 512, 0, stream>>>(e, slot_ik, rowp, colp,
          Bw + ((size_t)l * 3 + 0) * H_ * H_, Bb + ((size_t)l * 3 + 0) * H_,
          A3h, B2h, B3h, lneg + (size_t)l * H_, lneb + (size_t)l * H_, A1h);
      k_gather_ji<<<NE / TILE, 512, 0, stream>>>(e, slot_ji, rowp, colp, A2h, A1h);
    }
    k_node_update<<<NN / 4, 256, 0, stream>>>(h, A1h,
        lnhg + (size_t)l * H_, lnhb + (size_t)l * H_);
  }

  if (sorted) {
    k_h2bf<<<(NN * H_ / 4) / 256, 256, 0, stream>>>(h, h_bf);  // overwrites A1h (dead)
    k_score_mfma<<<NE / 128, 512, 0, stream>>>(e, rowp, colp, h_bf, s1w_packed,
                                               s1b, s2w, s2b, out);
  } else {
    k_score<<<NE / TILE, 512, 0, stream>>>(e, rowp, colp, h, s1w, s1b, s2w, s2b, out);
  }
}

// Round 6
// 3204.850 us; speedup vs baseline: 3.5161x; 1.3142x over previous
//
#include <hip/hip_runtime.h>
#include <math.h>

#define H_ 128
#define NN 50000
#define NE 800000
#define TILE 64

typedef unsigned short u16;
typedef __attribute__((ext_vector_type(8))) __bf16 bf16x8;
typedef __attribute__((ext_vector_type(4))) float f32x4;

__device__ __forceinline__ float red32(float v) {
  v += __shfl_xor(v, 1);
  v += __shfl_xor(v, 2);
  v += __shfl_xor(v, 4);
  v += __shfl_xor(v, 8);
  v += __shfl_xor(v, 16);
  return v;
}
__device__ __forceinline__ float red64(float v) { v = red32(v); v += __shfl_xor(v, 32); return v; }
__device__ __forceinline__ float sigm(float x) { return 1.0f / (1.0f + __expf(-x)); }
__device__ __forceinline__ float bf2f(u16 s) { return __uint_as_float(((unsigned)s) << 16); }
__device__ __forceinline__ u16 f2bf(float f) {
  unsigned u = __float_as_uint(f);
  return (u16)((u + 0x7FFFu + ((u >> 16) & 1u)) >> 16);
}

#define FMA16(acc, x0, x1, x2, x3, wv) \
  acc[0][0] = fmaf(x0, wv.x, acc[0][0]); acc[0][1] = fmaf(x0, wv.y, acc[0][1]); \
  acc[0][2] = fmaf(x0, wv.z, acc[0][2]); acc[0][3] = fmaf(x0, wv.w, acc[0][3]); \
  acc[1][0] = fmaf(x1, wv.x, acc[1][0]); acc[1][1] = fmaf(x1, wv.y, acc[1][1]); \
  acc[1][2] = fmaf(x1, wv.z, acc[1][2]); acc[1][3] = fmaf(x1, wv.w, acc[1][3]); \
  acc[2][0] = fmaf(x2, wv.x, acc[2][0]); acc[2][1] = fmaf(x2, wv.y, acc[2][1]); \
  acc[2][2] = fmaf(x2, wv.z, acc[2][2]); acc[2][3] = fmaf(x2, wv.w, acc[2][3]); \
  acc[3][0] = fmaf(x3, wv.x, acc[3][0]); acc[3][1] = fmaf(x3, wv.y, acc[3][1]); \
  acc[3][2] = fmaf(x3, wv.z, acc[3][2]); acc[3][3] = fmaf(x3, wv.w, acc[3][3]);

__global__ void k_sentinel(float* __restrict__ out, int n) {
  int i = blockIdx.x * 256 + threadIdx.x;
  if (i < n) out[i] = 3.0e30f;
}

// ---------------- sort machinery (once per call) ----------------

__global__ void k_count(const int* __restrict__ rowp, const int* __restrict__ colp,
                        int* __restrict__ cnt_row, int* __restrict__ cnt_col) {
  int i = blockIdx.x * 256 + threadIdx.x;
  if (i < NE) {
    atomicAdd(&cnt_col[colp[i]], 1);
    atomicAdd(&cnt_row[rowp[i]], 1);
  }
}

__global__ __launch_bounds__(1024) void k_scan2(
    const int* __restrict__ c0, int* __restrict__ o0,
    const int* __restrict__ c1, int* __restrict__ o1, int n)
{
  const int* c = blockIdx.x ? c1 : c0;
  int* o = blockIdx.x ? o1 : o0;
  __shared__ int warpsum[16];
  const int tid = threadIdx.x;
  int carry = 0;
  for (int basei = 0; basei < n; basei += 1024) {
    const int vidx = basei + tid;
    const int v = (vidx < n) ? c[vidx] : 0;
    int s = v;
#pragma unroll
    for (int d = 1; d < 64; d <<= 1) {
      int t = __shfl_up(s, d);
      if ((tid & 63) >= d) s += t;
    }
    if ((tid & 63) == 63) warpsum[tid >> 6] = s;
    __syncthreads();
    if (tid < 16) {
      int ws = warpsum[tid];
#pragma unroll
      for (int d = 1; d < 16; d <<= 1) {
        int t = __shfl_up(ws, d);
        if (tid >= d) ws += t;
      }
      warpsum[tid] = ws;
    }
    __syncthreads();
    const int wave = tid >> 6;
    const int prefix = (wave == 0 ? 0 : warpsum[wave - 1]) + carry;
    if (vidx < n) o[vidx] = s - v + prefix;
    carry += warpsum[15];
    __syncthreads();
  }
  if (tid == 0) o[n] = carry;
}

__global__ void k_copy_cur(const int* __restrict__ oc, const int* __restrict__ orr,
                           int* __restrict__ cc, int* __restrict__ cr) {
  int i = blockIdx.x * 256 + threadIdx.x;
  if (i < NN) { cc[i] = oc[i]; cr[i] = orr[i]; }
}

__global__ void k_fill(const int* __restrict__ rowp, const int* __restrict__ colp,
                       int* __restrict__ cur_col, int* __restrict__ cur_row,
                       int* __restrict__ slot_ji, int* __restrict__ slot_ik) {
  int i = blockIdx.x * 256 + threadIdx.x;
  if (i < NE) {
    int p = atomicAdd(&cur_col[colp[i]], 1);
    slot_ji[p] = i;
    int q = atomicAdd(&cur_row[rowp[i]], 1);
    slot_ik[q] = i;
  }
}

// ---------------- bf16 packing for MFMA ----------------

// s1w [384][128] f32 -> fragment-order bf16 (scorer)
__global__ void k_pack_s1w(const float* __restrict__ s1w, u16* __restrict__ packed) {
  int tid = blockIdx.x * 256 + threadIdx.x;
  if (tid < 49152) {
    const int e = tid & 7, l = (tid >> 3) & 63, nt = (tid >> 9) & 7, t = tid >> 12;
    const int k = t * 32 + (l >> 4) * 8 + e;
    const int n = nt * 16 + (l & 15);
    packed[tid] = f2bf(s1w[k * H_ + n]);
  }
}

// Bw[l][0] [128][128] f32 -> fragment-order bf16, 3 layers (16384 u16/layer)
__global__ void k_pack_bw0(const float* __restrict__ Bw, u16* __restrict__ packed) {
  int tid = blockIdx.x * 256 + threadIdx.x;
  if (tid < 49152) {
    const int lay = tid >> 14;
    const int idx = tid & 16383;
    const int e = idx & 7, l = (idx >> 3) & 63, nt = (idx >> 9) & 7, t = idx >> 12;
    const int k = t * 32 + (l >> 4) * 8 + e;
    const int n = nt * 16 + (l & 15);
    packed[tid] = f2bf(Bw[((size_t)lay * 3 + 0) * H_ * H_ + (size_t)k * H_ + n]);
  }
}

__global__ void k_h2bf(const float* __restrict__ h, u16* __restrict__ h_bf) {
  const int i = blockIdx.x * 256 + threadIdx.x;
  const float4 v = ((const float4*)h)[i];
  ushort4 p;
  p.x = f2bf(v.x); p.y = f2bf(v.y); p.z = f2bf(v.z); p.w = f2bf(v.w);
  ((ushort4*)h_bf)[i] = p;
}

// ---------------- encoders ----------------

__global__ __launch_bounds__(256) void k_node_enc(
    const float* __restrict__ x,
    const float* __restrict__ W11, const float* __restrict__ b11,
    const float* __restrict__ W12, const float* __restrict__ b12,
    const float* __restrict__ g1, const float* __restrict__ be1,
    float* __restrict__ h)
{
  __shared__ float sx[4][64];
  __shared__ float sv[4][130];
  const int w = threadIdx.x >> 6, lane = threadIdx.x & 63;
  const int node = blockIdx.x * 4 + w;
  sx[w][lane] = x[(size_t)node * 64 + lane];
  __syncthreads();
  const int t0 = lane * 2;
  float a0 = b11[t0], a1 = b11[t0 + 1];
#pragma unroll 8
  for (int k = 0; k < 64; ++k) {
    const float xk = sx[w][k];
    const float2 ww = *(const float2*)(W11 + (size_t)k * H_ + t0);
    a0 = fmaf(xk, ww.x, a0);
    a1 = fmaf(xk, ww.y, a1);
  }
  a0 = fmaxf(a0, 0.f); a1 = fmaxf(a1, 0.f);
  const float s = red64(a0 + a1);
  const float q = red64(a0 * a0 + a1 * a1);
  const float mean = s * (1.f / H_);
  const float rs = rsqrtf(q * (1.f / H_) - mean * mean + 1e-5f);
  sv[w][t0]     = (a0 - mean) * rs * g1[t0]     + be1[t0];
  sv[w][t0 + 1] = (a1 - mean) * rs * g1[t0 + 1] + be1[t0 + 1];
  __syncthreads();
  float c0 = b12[t0], c1 = b12[t0 + 1];
#pragma unroll 8
  for (int k = 0; k < H_; ++k) {
    const float vk = sv[w][k];
    const float2 ww = *(const float2*)(W12 + (size_t)k * H_ + t0);
    c0 = fmaf(vk, ww.x, c0);
    c1 = fmaf(vk, ww.y, c1);
  }
  h[(size_t)node * H_ + t0] = c0;
  h[(size_t)node * H_ + t0 + 1] = c1;
}

__global__ __launch_bounds__(512) void k_edge_enc(
    const float* __restrict__ ea,
    const float* __restrict__ W21, const float* __restrict__ b21,
    const float* __restrict__ W22, const float* __restrict__ b22,
    const float* __restrict__ g2, const float* __restrict__ be2,
    u16* __restrict__ e)
{
  __shared__ float sEA[TILE][36];
  __shared__ float sLN[TILE][130];
  const int tid = threadIdx.x;
  const int eg = tid >> 5, og = tid & 31;
  const int eg4 = eg * 4, t0 = og * 4;
  const size_t base = (size_t)blockIdx.x * TILE;
  {
    const int edge = tid >> 3, c4 = tid & 7;
    const float4 v = *(const float4*)(ea + (base + edge) * 32 + c4 * 4);
    *(float4*)(&sEA[edge][c4 * 4]) = v;
  }
  __syncthreads();

  const float4 b1 = *(const float4*)(b21 + t0);
  float a[4][4];
#pragma unroll
  for (int i = 0; i < 4; ++i) { a[i][0] = b1.x; a[i][1] = b1.y; a[i][2] = b1.z; a[i][3] = b1.w; }
#pragma unroll 8
  for (int k = 0; k < 32; ++k) {
    const float4 wv = *(const float4*)(W21 + (size_t)k * H_ + t0);
    const float x0 = sEA[eg4][k], x1 = sEA[eg4 + 1][k], x2 = sEA[eg4 + 2][k], x3 = sEA[eg4 + 3][k];
    FMA16(a, x0, x1, x2, x3, wv)
  }
  const float4 g4 = *(const float4*)(g2 + t0);
  const float4 bb = *(const float4*)(be2 + t0);
#pragma unroll
  for (int i = 0; i < 4; ++i) {
    const float r0 = fmaxf(a[i][0], 0.f), r1 = fmaxf(a[i][1], 0.f);
    const float r2 = fmaxf(a[i][2], 0.f), r3 = fmaxf(a[i][3], 0.f);
    const float s = red32(r0 + r1 + r2 + r3);
    const float q = red32(r0 * r0 + r1 * r1 + r2 * r2 + r3 * r3);
    const float mean = s * (1.f / H_);
    const float rs = rsqrtf(q * (1.f / H_) - mean * mean + 1e-5f);
    sLN[eg4 + i][t0]     = (r0 - mean) * rs * g4.x + bb.x;
    sLN[eg4 + i][t0 + 1] = (r1 - mean) * rs * g4.y + bb.y;
    sLN[eg4 + i][t0 + 2] = (r2 - mean) * rs * g4.z + bb.z;
    sLN[eg4 + i][t0 + 3] = (r3 - mean) * rs * g4.w + bb.w;
  }
  __syncthreads();

  const float4 b2 = *(const float4*)(b22 + t0);
  float c[4][4];
#pragma unroll
  for (int i = 0; i < 4; ++i) { c[i][0] = b2.x; c[i][1] = b2.y; c[i][2] = b2.z; c[i][3] = b2.w; }
#pragma unroll 4
  for (int k = 0; k < H_; ++k) {
    const float4 wv = *(const float4*)(W22 + (size_t)k * H_ + t0);
    const float x0 = sLN[eg4][k], x1 = sLN[eg4 + 1][k], x2 = sLN[eg4 + 2][k], x3 = sLN[eg4 + 3][k];
    FMA16(c, x0, x1, x2, x3, wv)
  }
#pragma unroll
  for (int i = 0; i < 4; ++i) {
    ushort4 pk;
    pk.x = f2bf(c[i][0]); pk.y = f2bf(c[i][1]); pk.z = f2bf(c[i][2]); pk.w = f2bf(c[i][3]);
    *(ushort4*)(e + (base + eg4 + i) * H_ + t0) = pk;
  }
}

// ---------------- per-layer node GEMMs ----------------

__global__ __launch_bounds__(512) void k_node_mats(
    const float* __restrict__ h,
    const float* __restrict__ Aw, const float* __restrict__ Ab,
    const float* __restrict__ Bw, const float* __restrict__ Bb,
    int l,
    float* __restrict__ A1h, u16* __restrict__ A2h, u16* __restrict__ A3h,
    u16* __restrict__ B2h, u16* __restrict__ B3h)
{
  __shared__ float sA[TILE][132];
  const int tid = threadIdx.x;
  const int eg = tid >> 5, og = tid & 31;
  const int eg4 = eg * 4, t0 = og * 4;
  const size_t base = (size_t)blockIdx.x * TILE;
#pragma unroll
  for (int p = 0; p < 4; ++p) {
    const int fid = tid + p * 512;
    const int r = fid >> 5, c4 = fid & 31;
    const float4 v = *(const float4*)(h + (base + r) * H_ + c4 * 4);
    *(float4*)(&sA[r][c4 * 4]) = v;
  }
  __syncthreads();

  const float* Wm[5]; const float* bm[5];
  Wm[0] = Aw + ((size_t)l * 3 + 0) * H_ * H_; bm[0] = Ab + ((size_t)l * 3 + 0) * H_;
  Wm[1] = Aw + ((size_t)l * 3 + 1) * H_ * H_; bm[1] = Ab + ((size_t)l * 3 + 1) * H_;
  Wm[2] = Aw + ((size_t)l * 3 + 2) * H_ * H_; bm[2] = Ab + ((size_t)l * 3 + 2) * H_;
  Wm[3] = Bw + ((size_t)l * 3 + 1) * H_ * H_; bm[3] = Bb + ((size_t)l * 3 + 1) * H_;
  Wm[4] = Bw + ((size_t)l * 3 + 2) * H_ * H_; bm[4] = Bb + ((size_t)l * 3 + 2) * H_;
  u16* om[5] = {0, A2h, A3h, B2h, B3h};

#pragma unroll 1
  for (int m = 0; m < 5; ++m) {
    const float4 bi = *(const float4*)(bm[m] + t0);
    float acc[4][4];
#pragma unroll
    for (int i = 0; i < 4; ++i) { acc[i][0] = bi.x; acc[i][1] = bi.y; acc[i][2] = bi.z; acc[i][3] = bi.w; }
    const float* W = Wm[m];
#pragma unroll 4
    for (int k = 0; k < H_; ++k) {
      const float4 wv = *(const float4*)(W + (size_t)k * H_ + t0);
      const float x0 = sA[eg4][k], x1 = sA[eg4 + 1][k], x2 = sA[eg4 + 2][k], x3 = sA[eg4 + 3][k];
      FMA16(acc, x0, x1, x2, x3, wv)
    }
#pragma unroll
    for (int i = 0; i < 4; ++i) {
      const size_t n = base + eg4 + i;
      if (n < (size_t)NN) {
        if (m == 0) {
          *(float4*)(A1h + n * H_ + t0) = make_float4(acc[i][0], acc[i][1], acc[i][2], acc[i][3]);
        } else {
          ushort4 pk;
          pk.x = f2bf(acc[i][0]); pk.y = f2bf(acc[i][1]); pk.z = f2bf(acc[i][2]); pk.w = f2bf(acc[i][3]);
          *(ushort4*)(om[m] + n * H_ + t0) = pk;
        }
      }
    }
  }
}

// ---------------- gated edge layer: MFMA B1e GEMM + post + segmented reduce ----------------

__global__ __launch_bounds__(512) void k_layer_edge2(
    u16* __restrict__ e,
    const int* __restrict__ slot_ik,
    const int* __restrict__ rowp, const int* __restrict__ colp,
    const u16* __restrict__ bwp,   // fragment-packed Bw0 for this layer (16384 u16)
    const float* __restrict__ Bb0,
    const u16* __restrict__ A3h,
    const u16* __restrict__ B2h, const u16* __restrict__ B3h,
    const float* __restrict__ lng, const float* __restrict__ lnb,
    float* __restrict__ A1h)
{
  __shared__ u16   sEb[TILE * H_];      // bf16 e-tile, XOR-swizzled rows (16 KB)
  __shared__ float sB1e[TILE][136];     // b1e result -> message buffer (34.8 KB)
  __shared__ int sEid[TILE];
  __shared__ int sRow[TILE];
  __shared__ int sCol[TILE];
  const int tid = threadIdx.x;
  const size_t base = (size_t)blockIdx.x * TILE;

  if (tid < TILE) {
    const int eid = slot_ik[base + tid];
    sEid[tid] = eid;
    sRow[tid] = rowp[eid];
    sCol[tid] = colp[eid];
  }
  __syncthreads();
  // stage gathered e rows as raw bf16 with G4 swizzle: byte ^= (row&7)<<4
#pragma unroll
  for (int p = 0; p < 4; ++p) {
    const int fid = tid + p * 512;
    const int j = fid >> 5, c4 = fid & 31;
    const ushort4 u = *(const ushort4*)(e + (size_t)sEid[j] * H_ + c4 * 4);
    *(ushort4*)((char*)sEb + ((j * 256 + c4 * 8) ^ ((j & 7) << 4))) = u;
  }
  __syncthreads();

  // ---- MFMA: b1e[64][128] = eTile[64][128] @ Bw0[128][128] (+bias) ----
  {
    const int w = tid >> 6, lane = tid & 63;
    const int mt = w & 3, nh = w >> 2;
    const int m16 = lane & 15, kg = lane >> 4;
    const int arow = mt * 16 + m16;
    f32x4 acc[4];
#pragma unroll
    for (int n4 = 0; n4 < 4; ++n4) { acc[n4][0]=0.f; acc[n4][1]=0.f; acc[n4][2]=0.f; acc[n4][3]=0.f; }
#pragma unroll
    for (int t = 0; t < 4; ++t) {
      const bf16x8 a = *(const bf16x8*)((const char*)sEb +
                          ((arow * 256 + t * 64 + kg * 16) ^ ((arow & 7) << 4)));
#pragma unroll
      for (int n4 = 0; n4 < 4; ++n4) {
        const bf16x8 b = *(const bf16x8*)(bwp + (((t * 8 + nh * 4 + n4) * 64 + lane) << 3));
        acc[n4] = __builtin_amdgcn_mfma_f32_16x16x32_bf16(a, b, acc[n4], 0, 0, 0);
      }
    }
#pragma unroll
    for (int n4 = 0; n4 < 4; ++n4) {
      const int feat = (nh * 4 + n4) * 16 + m16;
      const float bias = Bb0[feat];
#pragma unroll
      for (int r = 0; r < 4; ++r)
        sB1e[mt * 16 + kg * 4 + r][feat] = acc[n4][r] + bias;
    }
  }
  __syncthreads();

  // ---- post: gathers, dual LN, sigmoid, messages ----
  const int eg = tid >> 5, og = tid & 31;
  const int eg4 = eg * 4, t0 = og * 4;
  const float4 g4  = *(const float4*)(lng + t0);
  const float4 lb4 = *(const float4*)(lnb + t0);
#pragma unroll 1
  for (int i = 0; i < 4; ++i) {
    const int j = eg4 + i;
    const int eid = sEid[j];
    const int r = sRow[j], c = sCol[j];
    const float4 bv = *(const float4*)(&sB1e[j][t0]);
    const ushort4 ub2r = *(const ushort4*)(B2h + (size_t)r * H_ + t0);
    const ushort4 ub3c = *(const ushort4*)(B3h + (size_t)c * H_ + t0);
    const ushort4 ub2c = *(const ushort4*)(B2h + (size_t)c * H_ + t0);
    const ushort4 ub3r = *(const ushort4*)(B3h + (size_t)r * H_ + t0);
    const ushort4 ua3c = *(const ushort4*)(A3h + (size_t)c * H_ + t0);
    float pji[4], pik[4];
    pji[0] = fmaxf(bv.x + bf2f(ub2r.x) + bf2f(ub3c.x), 0.f);
    pji[1] = fmaxf(bv.y + bf2f(ub2r.y) + bf2f(ub3c.y), 0.f);
    pji[2] = fmaxf(bv.z + bf2f(ub2r.z) + bf2f(ub3c.z), 0.f);
    pji[3] = fmaxf(bv.w + bf2f(ub2r.w) + bf2f(ub3c.w), 0.f);
    pik[0] = fmaxf(bv.x + bf2f(ub2c.x) + bf2f(ub3r.x), 0.f);
    pik[1] = fmaxf(bv.y + bf2f(ub2c.y) + bf2f(ub3r.y), 0.f);
    pik[2] = fmaxf(bv.z + bf2f(ub2c.z) + bf2f(ub3r.z), 0.f);
    pik[3] = fmaxf(bv.w + bf2f(ub2c.w) + bf2f(ub3r.w), 0.f);
    const float sji = red32(pji[0] + pji[1] + pji[2] + pji[3]);
    const float qji = red32(pji[0]*pji[0] + pji[1]*pji[1] + pji[2]*pji[2] + pji[3]*pji[3]);
    const float sik = red32(pik[0] + pik[1] + pik[2] + pik[3]);
    const float qik = red32(pik[0]*pik[0] + pik[1]*pik[1] + pik[2]*pik[2] + pik[3]*pik[3]);
    const float mji = sji * (1.f / H_);
    const float rji = rsqrtf(qji * (1.f / H_) - mji * mji + 1e-5f);
    const float mik = sik * (1.f / H_);
    const float rik = rsqrtf(qik * (1.f / H_) - mik * mik + 1e-5f);
    const ushort4 ueo = *(const ushort4*)((const char*)sEb +
                          ((j * 256 + t0 * 2) ^ ((j & 7) << 4)));
    const float eo0 = bf2f(ueo.x), eo1 = bf2f(ueo.y);
    const float eo2 = bf2f(ueo.z), eo3 = bf2f(ueo.w);
    ushort4 pkji;
    pkji.x = f2bf(eo0 + (pji[0] - mji) * rji * g4.x + lb4.x);
    pkji.y = f2bf(eo1 + (pji[1] - mji) * rji * g4.y + lb4.y);
    pkji.z = f2bf(eo2 + (pji[2] - mji) * rji * g4.z + lb4.z);
    pkji.w = f2bf(eo3 + (pji[3] - mji) * rji * g4.w + lb4.w);
    *(ushort4*)(e + (size_t)eid * H_ + t0) = pkji;
    const float e0 = eo0 + (pik[0] - mik) * rik * g4.x + lb4.x;
    const float e1 = eo1 + (pik[1] - mik) * rik * g4.y + lb4.y;
    const float e2 = eo2 + (pik[2] - mik) * rik * g4.z + lb4.z;
    const float e3 = eo3 + (pik[3] - mik) * rik * g4.w + lb4.w;
    const float sg0 = sigm(e0), sg1 = sigm(e1), sg2 = sigm(e2), sg3 = sigm(e3);
    const float S = red32(sg0 + sg1 + sg2 + sg3);
    const float inv = 1.f / (S + 1e-6f);
    sB1e[j][t0]     = bf2f(ua3c.x) * sg0 * inv;
    sB1e[j][t0 + 1] = bf2f(ua3c.y) * sg1 * inv;
    sB1e[j][t0 + 2] = bf2f(ua3c.z) * sg2 * inv;
    sB1e[j][t0 + 3] = bf2f(ua3c.w) * sg3 * inv;
  }
  __syncthreads();

  // segmented reduction by destination row (sRow non-decreasing)
  const int f = tid & 127;
  const int sgrp = tid >> 7;
  int seg = 0, j = 0;
  while (j < TILE) {
    const int r = sRow[j];
    int jend = j + 1;
    while (jend < TILE && sRow[jend] == r) ++jend;
    if ((seg & 3) == sgrp) {
      float s = 0.f;
      for (int k2 = j; k2 < jend; ++k2) s += sB1e[k2][f];
      atomicAdd(&A1h[(size_t)r * H_ + f], s);
    }
    ++seg; j = jend;
  }
}

// Pass 2 (col-sorted): read updated e (= e_ji), segment-reduce m_ji by col.
__global__ __launch_bounds__(512) void k_gather_ji(
    const u16* __restrict__ e,
    const int* __restrict__ slot_ji,
    const int* __restrict__ rowp, const int* __restrict__ colp,
    const u16* __restrict__ A2h,
    float* __restrict__ A1h)
{
  __shared__ float sM[TILE][132];
  __shared__ int sEid[TILE];
  __shared__ int sRow[TILE];
  __shared__ int sCol[TILE];
  const int tid = threadIdx.x;
  const int eg = tid >> 5, og = tid & 31;
  const int eg4 = eg * 4, t0 = og * 4;
  const size_t base = (size_t)blockIdx.x * TILE;

  if (tid < TILE) {
    const int eid = slot_ji[base + tid];
    sEid[tid] = eid;
    sRow[tid] = rowp[eid];
    sCol[tid] = colp[eid];
  }
  __syncthreads();

#pragma unroll 1
  for (int i = 0; i < 4; ++i) {
    const int j = eg4 + i;
    const int eid = sEid[j];
    const int r = sRow[j];
    const ushort4 ue = *(const ushort4*)(e + (size_t)eid * H_ + t0);
    const float sg0 = sigm(bf2f(ue.x));
    const float sg1 = sigm(bf2f(ue.y));
    const float sg2 = sigm(bf2f(ue.z));
    const float sg3 = sigm(bf2f(ue.w));
    const float S = red32(sg0 + sg1 + sg2 + sg3);
    const float inv = 1.f / (S + 1e-6f);
    const ushort4 ua = *(const ushort4*)(A2h + (size_t)r * H_ + t0);
    sM[j][t0]     = bf2f(ua.x) * sg0 * inv;
    sM[j][t0 + 1] = bf2f(ua.y) * sg1 * inv;
    sM[j][t0 + 2] = bf2f(ua.z) * sg2 * inv;
    sM[j][t0 + 3] = bf2f(ua.w) * sg3 * inv;
  }
  __syncthreads();

  const int f = tid & 127;
  const int sgrp = tid >> 7;
  int seg = 0, j = 0;
  while (j < TILE) {
    const int c = sCol[j];
    int jend = j + 1;
    while (jend < TILE && sCol[jend] == c) ++jend;
    if ((seg & 3) == sgrp) {
      float s = 0.f;
      for (int k2 = j; k2 < jend; ++k2) s += sM[k2][f];
      atomicAdd(&A1h[(size_t)c * H_ + f], s);
    }
    ++seg; j = jend;
  }
}

// ---------------- node update ----------------

__global__ __launch_bounds__(256) void k_node_update(
    float* __restrict__ h, const float* __restrict__ A1h,
    const float* __restrict__ g, const float* __restrict__ b)
{
  const int w = threadIdx.x >> 6, lane = threadIdx.x & 63;
  const size_t node = (size_t)blockIdx.x * 4 + w;
  const int t0 = lane * 2;
  const float2 a = *(const float2*)(A1h + node * H_ + t0);
  const float u0 = fmaxf(a.x, 0.f);
  const float u1 = fmaxf(a.y, 0.f);
  const float sm = red64(u0 + u1);
  const float sq = red64(u0 * u0 + u1 * u1);
  const float mean = sm * (1.f / H_);
  const float rs = rsqrtf(sq * (1.f / H_) - mean * mean + 1e-5f);
  float2 hv = *(float2*)(h + node * H_ + t0);
  hv.x += (u0 - mean) * rs * g[t0] + b[t0];
  hv.y += (u1 - mean) * rs * g[t0 + 1] + b[t0 + 1];
  *(float2*)(h + node * H_ + t0) = hv;
}

// ---------------- MFMA scorer ----------------

__global__ __launch_bounds__(512) void k_score_mfma(
    const u16* __restrict__ e, const int* __restrict__ rowp, const int* __restrict__ colp,
    const u16* __restrict__ h_bf, const u16* __restrict__ s1w_packed,
    const float* __restrict__ s1b, const float* __restrict__ s2w,
    const float* __restrict__ s2b, float* __restrict__ out)
{
  __shared__ u16 sB[8 * 64 * 8];
  const int tid = threadIdx.x;
  const int w = tid >> 6, lane = tid & 63;
  const int m16 = lane & 15, kg = lane >> 4;
  const size_t gbase = (size_t)blockIdx.x * 128;
  const int eidx = (int)gbase + w * 16 + m16;
  const int r_ = rowp[eidx], c_ = colp[eidx];
  const u16* srcA0 = h_bf + (size_t)r_ * H_;
  const u16* srcA1 = h_bf + (size_t)c_ * H_;
  const u16* srcA2 = e + (size_t)eidx * H_;

  f32x4 acc[8];
#pragma unroll
  for (int nt = 0; nt < 8; ++nt) { acc[nt][0] = 0.f; acc[nt][1] = 0.f; acc[nt][2] = 0.f; acc[nt][3] = 0.f; }

#pragma unroll 1
  for (int t = 0; t < 12; ++t) {
    __syncthreads();
    {
      const uint4* src = (const uint4*)(s1w_packed + (size_t)t * 4096);
      ((uint4*)sB)[tid] = src[tid];
    }
    __syncthreads();
    const u16* sa = (t < 4) ? srcA0 : (t < 8) ? srcA1 : srcA2;
    const int tt = t & 3;
    const bf16x8 a = *(const bf16x8*)(sa + tt * 32 + kg * 8);
#pragma unroll
    for (int nt = 0; nt < 8; ++nt) {
      const bf16x8 b = *(const bf16x8*)(sB + nt * 512 + lane * 8);
      acc[nt] = __builtin_amdgcn_mfma_f32_16x16x32_bf16(a, b, acc[nt], 0, 0, 0);
    }
  }

  float partial[4] = {0.f, 0.f, 0.f, 0.f};
#pragma unroll
  for (int nt = 0; nt < 8; ++nt) {
    const int c = nt * 16 + m16;
    const float sb1 = s1b[c];
    const float w2 = s2w[c];
#pragma unroll
    for (int r = 0; r < 4; ++r)
      partial[r] += fmaxf(acc[nt][r] + sb1, 0.f) * w2;
  }
  const float b2 = s2b[0];
#pragma unroll
  for (int r = 0; r < 4; ++r) {
    float v = partial[r];
    v += __shfl_xor(v, 1); v += __shfl_xor(v, 2);
    v += __shfl_xor(v, 4); v += __shfl_xor(v, 8);
    if (m16 == 0) out[gbase + w * 16 + kg * 4 + r] = v + b2;
  }
}

extern "C" void kernel_launch(void* const* d_in, const int* in_sizes, int n_in,
                              void* d_out, int out_size, void* d_ws, size_t ws_size,
                              hipStream_t stream) {
  const float* x    = (const float*)d_in[0];
  const float* ea   = (const float*)d_in[1];
  const int*   eidx = (const int*)d_in[2];
  const float* W11w = (const float*)d_in[3];
  const float* W11b = (const float*)d_in[4];
  const float* W12w = (const float*)d_in[5];
  const float* W12b = (const float*)d_in[6];
  const float* W21w = (const float*)d_in[7];
  const float* W21b = (const float*)d_in[8];
  const float* W22w = (const float*)d_in[9];
  const float* W22b = (const float*)d_in[10];
  const float* ln1g = (const float*)d_in[11];
  const float* ln1b = (const float*)d_in[12];
  const float* ln2g = (const float*)d_in[13];
  const float* ln2b = (const float*)d_in[14];
  const float* Aw   = (const float*)d_in[15];
  const float* Ab   = (const float*)d_in[16];
  const float* Bw   = (const float*)d_in[17];
  const float* Bb   = (const float*)d_in[18];
  const float* lnhg = (const float*)d_in[19];
  const float* lnhb = (const float*)d_in[20];
  const float* lneg = (const float*)d_in[21];
  const float* lneb = (const float*)d_in[22];
  const float* s1w  = (const float*)d_in[23];
  const float* s1b  = (const float*)d_in[24];
  const float* s2w  = (const float*)d_in[25];
  const float* s2b  = (const float*)d_in[26];
  float* out = (float*)d_out;

  k_sentinel<<<(out_size + 255) / 256, 256, 0, stream>>>(out, out_size);

  const size_t need = 314624000;
  if (ws_size < need) return;  // sentinel (3e30) signals this

  char* wsb = (char*)d_ws;
  u16*   e   = (u16*)wsb;                        // [NE][128] bf16   204.8 MB
  float* h   = (float*)(wsb + 204800000);        // [NN][128] f32     25.6 MB
  float* A1h = (float*)(wsb + 230400000);        // [NN][128] f32     25.6 MB
  u16*   A2h = (u16*)(wsb + 256000000);          // [NN][128] bf16    12.8 MB
  u16*   A3h = (u16*)(wsb + 268800000);
  u16*   B2h = (u16*)(wsb + 281600000);
  u16*   B3h = (u16*)(wsb + 294400000);
  int*   slot_ji  = (int*)(wsb + 307200000);     // [NE] col-sorted    3.2 MB
  int*   slot_ik  = (int*)(wsb + 310400000);     // [NE] row-sorted    3.2 MB
  int*   offs_col = (int*)(wsb + 313600000);     // [NN+1] (dead after copy_cur)
  int*   offs_row = (int*)(wsb + 313856000);
  int*   cur_col  = (int*)(wsb + 314112000);     // (dead after fill)
  int*   cur_row  = (int*)(wsb + 314368000);
  // overlays on dead regions:
  u16*   h_bf       = (u16*)(wsb + 230400000);   // over A1h (dead after last node_update)
  u16*   s1w_packed = (u16*)(wsb + 314112000);   // over cur_col   (96 KB)
  u16*   bw0_packed = (u16*)(wsb + 313600000);   // over offs_col  (96 KB)

  const int* rowp = eidx;
  const int* colp = eidx + NE;

  k_node_enc<<<NN / 4, 256, 0, stream>>>(x, W11w, W11b, W12w, W12b, ln1g, ln1b, h);
  k_edge_enc<<<NE / TILE, 512, 0, stream>>>(ea, W21w, W21b, W22w, W22b, ln2g, ln2b, e);

  hipMemsetAsync(cur_col, 0, (size_t)NN * sizeof(int), stream);
  hipMemsetAsync(cur_row, 0, (size_t)NN * sizeof(int), stream);
  k_count<<<(NE + 255) / 256, 256, 0, stream>>>(rowp, colp, cur_row, cur_col);
  k_scan2<<<2, 1024, 0, stream>>>(cur_col, offs_col, cur_row, offs_row, NN);
  k_copy_cur<<<(NN + 255) / 256, 256, 0, stream>>>(offs_col, offs_row, cur_col, cur_row);
  k_fill<<<(NE + 255) / 256, 256, 0, stream>>>(rowp, colp, cur_col, cur_row, slot_ji, slot_ik);
  k_pack_s1w<<<192, 256, 0, stream>>>(s1w, s1w_packed);   // overwrites cur_col (dead)
  k_pack_bw0<<<192, 256, 0, stream>>>(Bw, bw0_packed);    // overwrites offs_col (dead)

  for (int l = 0; l < 3; ++l) {
    k_node_mats<<<(NN + TILE - 1) / TILE, 512, 0, stream>>>(h, Aw, Ab, Bw, Bb, l,
                                                            A1h, A2h, A3h, B2h, B3h);
    k_layer_edge2<<<NE / TILE, 512, 0, stream>>>(e, slot_ik, rowp, colp,
        bw0_packed + (size_t)l * 16384, Bb + ((size_t)l * 3 + 0) * H_,
        A3h, B2h, B3h, lneg + (size_t)l * H_, lneb + (size_t)l * H_, A1h);
    k_gather_ji<<<NE / TILE, 512, 0, stream>>>(e, slot_ji, rowp, colp, A2h, A1h);
    k_node_update<<<NN / 4, 256, 0, stream>>>(h, A1h,
        lnhg + (size_t)l * H_, lnhb + (size_t)l * H_);
  }

  k_h2bf<<<(NN * H_ / 4) / 256, 256, 0, stream>>>(h, h_bf);  // overwrites A1h (dead)
  k_score_mfma<<<NE / 128, 512, 0, stream>>>(e, rowp, colp, h_bf, s1w_packed,
                                             s1b, s2w, s2b, out);
}